// Round 3
// baseline (560.671 us; speedup 1.0000x reference)
//
#include <hip/hip_runtime.h>
#include <hip/hip_bf16.h>

typedef __hip_bfloat16 bf16;
typedef __bf16 bf16v8 __attribute__((ext_vector_type(8)));
typedef float f32x4 __attribute__((ext_vector_type(4)));

#define BB    128
#define DIM   384
#define NTOK  256
#define NH    8
#define KD    32
#define DHEAD 128
#define DH    1024
#define SCALE 0.17677669529663687f

// sanitize boundary reads: NaN->0, clamp huge
static __device__ __forceinline__ float sf(float x) {
  return (x == x) ? fminf(fmaxf(x, -1e4f), 1e4f) : 0.f;
}

static __device__ __forceinline__ float rfl(float x) {
  return __int_as_float(__builtin_amdgcn_readfirstlane(__float_as_int(x)));
}

#define GLOAD_LDS16(gsrc, ldst)                                                \
  __builtin_amdgcn_global_load_lds(                                            \
      (const __attribute__((address_space(1))) void*)(gsrc),                   \
      (__attribute__((address_space(3))) void*)(ldst), 16, 0, 0)

// ---------------- K-1a: fp32 weights -> bf16 copies in ws ----------------
__global__ __launch_bounds__(256) void k_convert(const float* __restrict__ qw,
    const float* __restrict__ kw, const float* __restrict__ vw,
    const float* __restrict__ pw, bf16* __restrict__ dst) {
  int i = blockIdx.x * 256 + threadIdx.x;
  float v;
  if (i < 98304)       v = qw[i];
  else if (i < 196608) v = kw[i - 98304];
  else if (i < 589824) v = vw[i - 196608];
  else                 v = pw[i - 589824];
  dst[i] = __float2bfloat16(sf(v));
}

// ---------------- K-1b: bmix[g][n][m] = th1_b[g] + sum_h th1[g][h]*bias[h][idxs[n][m]] ----------------
// TH1's bias path folded in (batch-independent).
__global__ __launch_bounds__(256) void k_bias(const float* __restrict__ ab,
    const int* __restrict__ idxs, int n_off,
    const float* __restrict__ th1_w, const float* __restrict__ th1_b,
    float* __restrict__ bias_full) {
  int nm = blockIdx.x * 256 + threadIdx.x;   // 65536 positions
  int idx = idxs[nm];
  float bh[8];
#pragma unroll
  for (int h = 0; h < 8; ++h) bh[h] = sf(ab[h * n_off + idx]);
#pragma unroll
  for (int g = 0; g < 8; ++g) {
    float a = sf(th1_b[g]);
#pragma unroll
    for (int h = 0; h < 8; ++h) a += sf(th1_w[g * 8 + h]) * bh[h];
    bias_full[(size_t)g * 65536 + nm] = a;
  }
}

// ---------------- K0: x fp32 [cb,384,256] -> xT bf16 [cb,256,384] ----------------
__global__ __launch_bounds__(256) void k_transpose_x(const float* __restrict__ x,
                                                     bf16* __restrict__ xT) {
  __shared__ bf16 tile[32][33];
  int b = blockIdx.z;
  int c0 = blockIdx.x * 32;
  int n0 = blockIdx.y * 32;
  int t = threadIdx.x;
  int tn = t & 31, tc = t >> 5;
#pragma unroll
  for (int p = 0; p < 4; ++p)
    tile[tc + p * 8][tn] =
        __float2bfloat16(sf(x[((size_t)b * DIM + c0 + tc + p * 8) * NTOK + n0 + tn]));
  __syncthreads();
  int wc = t & 31, wn = t >> 5;
#pragma unroll
  for (int p = 0; p < 4; ++p)
    xT[((size_t)b * NTOK + n0 + wn + p * 8) * DIM + c0 + wc] = tile[wc][wn + p * 8];
}

// ---------------- K1: QKV GEMM, LDS-staged m97-style ----------------
__global__ __launch_bounds__(256, 3) void k_qkv(const bf16* __restrict__ xT,
    const bf16* __restrict__ W, const float* __restrict__ q_b,
    const float* __restrict__ k_b, const float* __restrict__ v_b,
    bf16* __restrict__ qT, bf16* __restrict__ kT, bf16* __restrict__ v4,
    int nb) {
  __shared__ __align__(16) char smem[34816];   // stage A16K+B16K | v-epilogue tile 128x136 bf16
  bf16* sA = (bf16*)smem;                      // [128][64]
  bf16* sB = (bf16*)(smem + 16384);            // [128][64]
  bf16* actt = (bf16*)smem;                    // [128][136]

  int id = blockIdx.x;
  int b, tile;
  if ((nb & 7) == 0) {
    int per = nb >> 3;
    int xcd = id & 7, slot = id >> 3;
    b = xcd * per + (slot % per);
    tile = slot / per;          // [0,24)
  } else { b = id / 24; tile = id % 24; }
  int mt = tile >> 1, nt = tile & 1;
  int m0 = mt * 128, n0b = nt * 128;
  int t = threadIdx.x;
  int wave = t >> 6, lane = t & 63;
  int wm = wave >> 1, wn = wave & 1;
  int qd = lane >> 4, li = lane & 15;
  const bf16* xTb = xT + ((size_t)b * NTOK + n0b) * DIM;

  f32x4 acc[4][4];
#pragma unroll
  for (int r = 0; r < 4; ++r)
#pragma unroll
    for (int f = 0; f < 4; ++f) acc[r][f] = (f32x4){0.f, 0.f, 0.f, 0.f};

  for (int ks = 0; ks < 6; ++ks) {
    int k0 = ks * 64;
    __syncthreads();            // prev compute done -> safe to overwrite LDS
#pragma unroll
    for (int i = 0; i < 8; ++i) {
      int g = wave * 512 + i * 64 + lane;      // [0,2048) granules; <1024 -> A
      int gg = g & 1023;
      int row = gg >> 3, slot = gg & 7;
      int col = ((slot ^ (row & 7)) << 3) + k0;
      const bf16* src = (g < 1024)
          ? (W + (size_t)(m0 + row) * DIM + col)
          : (xTb + (size_t)row * DIM + col);
      GLOAD_LDS16(src, smem + (size_t)(wave * 512 + i * 64) * 16);
    }
    __syncthreads();            // staging drained (vmcnt(0) at barrier)
#pragma unroll
    for (int s = 0; s < 2; ++s) {
      bf16v8 Afr[4], Bfr[4];
#pragma unroll
      for (int r = 0; r < 4; ++r) {
        int row = wm * 64 + r * 16 + li;
        Afr[r] = *(const bf16v8*)(sA + row * 64 + (((s * 4 + qd) ^ (row & 7)) << 3));
      }
#pragma unroll
      for (int f = 0; f < 4; ++f) {
        int row = wn * 64 + f * 16 + li;
        Bfr[f] = *(const bf16v8*)(sB + row * 64 + (((s * 4 + qd) ^ (row & 7)) << 3));
      }
#pragma unroll
      for (int r = 0; r < 4; ++r)
#pragma unroll
        for (int f = 0; f < 4; ++f)
          acc[r][f] = __builtin_amdgcn_mfma_f32_16x16x32_bf16(Afr[r], Bfr[f], acc[r][f], 0, 0, 0);
    }
  }
  __syncthreads();              // all LDS reads done before smem reuse

  if (m0 >= 512) {
    // ---- v rows: restage through LDS -> coalesced 16B stores to v4[ch][tok] ----
    int ch0 = m0 - 512;
#pragma unroll
    for (int r = 0; r < 4; ++r)
#pragma unroll
      for (int f = 0; f < 4; ++f) {
        int coll = wn * 64 + f * 16 + li;
#pragma unroll
        for (int rr = 0; rr < 4; ++rr) {
          int rowl = wm * 64 + r * 16 + qd * 4 + rr;
          actt[rowl * 136 + coll] =
              __float2bfloat16(acc[r][f][rr] + sf(v_b[ch0 + rowl]));
        }
      }
    __syncthreads();
#pragma unroll
    for (int it = 0; it < 8; ++it) {
      int g = it * 256 + t;
      int row = g >> 4, c16 = g & 15;
      bf16v8 vv = *(const bf16v8*)(actt + row * 136 + c16 * 8);
      *(bf16v8*)(v4 + ((size_t)b * DH + ch0 + row) * NTOK + n0b + c16 * 8) = vv;
    }
  } else {
    // ---- q/k rows: packed 8B stores (4 consecutive kd per thread) ----
    const float* bias = (m0 < 256) ? q_b : k_b;
    bf16* dst = (m0 < 256) ? qT : kT;
    int mb = (m0 < 256) ? m0 : m0 - 256;
#pragma unroll
    for (int r = 0; r < 4; ++r)
#pragma unroll
      for (int f = 0; f < 4; ++f) {
        int n = n0b + wn * 64 + f * 16 + li;
        int rowg = mb + wm * 64 + r * 16 + qd * 4;
        int h = rowg >> 5, kd = rowg & 31;
        union { bf16 e[4]; uint2 u; } pk;
#pragma unroll
        for (int rr = 0; rr < 4; ++rr)
          pk.e[rr] = __float2bfloat16(acc[r][f][rr] + sf(bias[rowg + rr]));
        *(uint2*)(dst + (((size_t)b * NH + h) * NTOK + n) * KD + kd) = pk.u;
      }
  }
}

// ---------------- K2: scores + TH1(folded bias, SGPR weights) + softmax + TH2 -> P ----------------
__global__ __launch_bounds__(512, 2) void k_scores(const bf16* __restrict__ qT,
    const bf16* __restrict__ kT, const float* __restrict__ bias_full,
    const float* __restrict__ th1_w,
    const float* __restrict__ th2_w, const float* __restrict__ th2_b,
    bf16* __restrict__ P, int nb) {
  __shared__ bf16 stage[4][8][16][32];   // 32 KB: [g2 round][wave][nl][m]
  __shared__ float s_th1[64], s_th2[64], s_t2b[8];
  __shared__ float s_part[8][8][16];
  __shared__ float s_invl[8][16];
  int t = threadIdx.x;
  // prescale TH1 weights by SCALE (bias path already folded into bias_full)
  if (t < 64) { s_th1[t] = sf(th1_w[t]) * SCALE; s_th2[t] = sf(th2_w[t]); }
  if (t >= 64 && t < 72) s_t2b[t - 64] = sf(th2_b[t - 64]);
  int id = blockIdx.x;
  int b, nt;
  if ((nb & 7) == 0) {
    int per = nb >> 3;
    int xcd = id & 7, slot = id >> 3;
    b = xcd * per + (slot % per);
    nt = slot / per;            // [0,16)
  } else { b = id >> 4; nt = id & 15; }
  int n0 = nt * 16;
  int wave = t >> 6, lane = t & 63, qd = lane >> 4, li = lane & 15;
  int ms = wave * 32;

  // ---- QK^T: S[h][mt][r] at (n = n0+qd*4+r, m = ms+mt*16+li) ----
  f32x4 S[8][2];
#pragma unroll
  for (int h = 0; h < 8; ++h) {
    bf16v8 Af = *(const bf16v8*)(qT + (((size_t)b * NH + h) * NTOK + n0 + li) * KD + qd * 8);
#pragma unroll
    for (int mt = 0; mt < 2; ++mt) {
      bf16v8 Bf = *(const bf16v8*)(kT + (((size_t)b * NH + h) * NTOK + ms + mt * 16 + li) * KD + qd * 8);
      f32x4 c = {0.f, 0.f, 0.f, 0.f};
      S[h][mt] = __builtin_amdgcn_mfma_f32_16x16x32_bf16(Af, Bf, c, 0, 0, 0);
    }
  }
  __syncthreads();   // th weights staged in LDS

  // ---- TH1 (SGPR weights) + premixed bias + exp + row sums ----
  float psum[8][4];
#pragma unroll
  for (int g = 0; g < 8; ++g)
#pragma unroll
    for (int r = 0; r < 4; ++r) psum[g][r] = 0.f;
  {
    float w1[64];
#pragma unroll
    for (int i = 0; i < 64; ++i) w1[i] = rfl(s_th1[i]);
#pragma unroll
    for (int mt = 0; mt < 2; ++mt)
#pragma unroll
      for (int r = 0; r < 4; ++r) {
        float e8[8];
#pragma unroll
        for (int g = 0; g < 8; ++g) {
          float a = bias_full[(size_t)(g * NTOK + n0 + qd * 4 + r) * NTOK + ms + mt * 16 + li];
#pragma unroll
          for (int h = 0; h < 8; ++h) a += w1[g * 8 + h] * S[h][mt][r];
          e8[g] = __expf(fminf(a, 30.0f));
          psum[g][r] += e8[g];
        }
#pragma unroll
        for (int g = 0; g < 8; ++g) S[g][mt][r] = e8[g];
      }
  }
#pragma unroll
  for (int g = 0; g < 8; ++g)
#pragma unroll
    for (int r = 0; r < 4; ++r) {
      float v = psum[g][r];
      v += __shfl_xor(v, 1, 64);
      v += __shfl_xor(v, 2, 64);
      v += __shfl_xor(v, 4, 64);
      v += __shfl_xor(v, 8, 64);
      psum[g][r] = v;
    }
  if (li == 0) {
#pragma unroll
    for (int g = 0; g < 8; ++g)
#pragma unroll
      for (int r = 0; r < 4; ++r) s_part[wave][g][qd * 4 + r] = psum[g][r];
  }
  __syncthreads();
  if (t < 128) {
    int g = t >> 4, n = t & 15;
    float ssum = 0.f;
#pragma unroll
    for (int w2 = 0; w2 < 8; ++w2) ssum += s_part[w2][g][n];
    s_invl[g][n] = 1.0f / ssum;
  }
  __syncthreads();
#pragma unroll
  for (int g = 0; g < 8; ++g)
#pragma unroll
    for (int mt = 0; mt < 2; ++mt)
#pragma unroll
      for (int r = 0; r < 4; ++r)
        S[g][mt][r] *= s_invl[g][qd * 4 + r];

  // ---- TH2 (SGPR weights) + blocked-coalesced P store via LDS restage ----
  size_t pb = (size_t)b * NH * 65536 + (size_t)nt * 4096 + wave * 512 + lane * 8;
  {
    float w2[64], b2[8];
#pragma unroll
    for (int i = 0; i < 64; ++i) w2[i] = rfl(s_th2[i]);
#pragma unroll
    for (int i = 0; i < 8; ++i) b2[i] = rfl(s_t2b[i]);
#pragma unroll
    for (int gr = 0; gr < 2; ++gr) {
#pragma unroll
      for (int g2i = 0; g2i < 4; ++g2i) {
        int g2 = gr * 4 + g2i;
#pragma unroll
        for (int mt = 0; mt < 2; ++mt)
#pragma unroll
          for (int r = 0; r < 4; ++r) {
            float a = b2[g2];
#pragma unroll
            for (int g = 0; g < 8; ++g) a += w2[g2 * 8 + g] * S[g][mt][r];
            stage[g2i][wave][qd * 4 + r][mt * 16 + li] = __float2bfloat16(a);
          }
      }
      __syncthreads();
#pragma unroll
      for (int g2i = 0; g2i < 4; ++g2i) {
        int g2 = gr * 4 + g2i;
        bf16v8 vv = *(const bf16v8*)&stage[g2i][wave][lane >> 2][(lane & 3) * 8];
        *(bf16v8*)(P + pb + (size_t)g2 * 65536) = vv;
      }
      __syncthreads();
    }
  }
}

// ---------------- K3: O = P@V + dwconv + relu -> act[b,n,ch] ----------------
static __device__ __forceinline__ int vswz(int ch, int tok) {
  return tok ^ ((ch & 7) << 3);
}

__global__ __launch_bounds__(512, 1) void k_pv(const bf16* __restrict__ P,
    const bf16* __restrict__ v4,
    const float* __restrict__ vl_w, const float* __restrict__ vl_b,
    bf16* __restrict__ act, int nb) {
  __shared__ bf16 v_s[128][256];     // 64 KB, bank-swizzled via vswz()
  __shared__ bf16 act_s[256][136];   // 68 KB (+8 pad)
  __shared__ float wv_s[1152];       // dw weights for this head: 4.5 KB
  __shared__ float vb_s[128];
  int id = blockIdx.x;
  int b, h;
  if ((nb & 7) == 0) {
    int per = nb >> 3;
    int xcd = id & 7, slot = id >> 3;
    b = xcd * per + (slot % per);
    h = slot / per;            // [0,8)
  } else { b = id >> 3; h = id & 7; }
  int t = threadIdx.x;
  int wave = t >> 6, lane = t & 63;
  int qd = lane >> 4, li = lane & 15;
  int nw = wave * 32;                // 32 tokens per wave
  int nwt = wave * 2;                // n-tile base
  const bf16* Pb = P + ((size_t)b * NH + h) * 65536;
  const bf16* Vb = v4 + ((size_t)b * DH + h * DHEAD) * NTOK;

  // --- prefetch ALL P fragments (latency hides under V staging; drained by barrier) ---
  bf16v8 Af[4][2][2];
#pragma unroll
  for (int mi = 0; mi < 4; ++mi)
#pragma unroll
    for (int s = 0; s < 2; ++s)
#pragma unroll
      for (int r = 0; r < 2; ++r)
        Af[mi][s][r] = *(const bf16v8*)(Pb + (size_t)(nwt + r) * 4096 +
                                        (mi * 2 + s) * 512 + li * 32 + qd * 8);

  // --- stage V slab (coalesced 16B, swizzled LDS dest) + dw weights ---
#pragma unroll
  for (int p = 0; p < 8; ++p) {
    int idx = p * 512 + t;             // 16-B granule id, 4096 total
    int ch = idx >> 5, tok = (idx & 31) * 8;
    *(bf16v8*)&v_s[ch][vswz(ch, tok)] = *(const bf16v8*)(Vb + (size_t)ch * NTOK + tok);
  }
  for (int i = t; i < 1152; i += 512) wv_s[i] = sf(vl_w[(size_t)h * DHEAD * 9 + i]);
  if (t < 128) vb_s[t] = sf(vl_b[h * DHEAD + t]);
  __syncthreads();

  // --- PV GEMM: B operand from swizzled LDS ---
  f32x4 acc[2][8];
#pragma unroll
  for (int r = 0; r < 2; ++r)
#pragma unroll
    for (int f = 0; f < 8; ++f) acc[r][f] = (f32x4){0.f, 0.f, 0.f, 0.f};
#pragma unroll
  for (int mi = 0; mi < 4; ++mi) {
    int m0 = mi * 64;
#pragma unroll
    for (int s = 0; s < 2; ++s) {
      bf16v8 Bf[8];
#pragma unroll
      for (int f = 0; f < 8; ++f) {
        int ch = f * 16 + li;
        Bf[f] = *(const bf16v8*)&v_s[ch][vswz(ch, m0 + s * 32 + qd * 8)];
      }
#pragma unroll
      for (int f = 0; f < 8; ++f)
#pragma unroll
        for (int r = 0; r < 2; ++r)
          acc[r][f] = __builtin_amdgcn_mfma_f32_16x16x32_bf16(Af[mi][s][r], Bf[f], acc[r][f], 0, 0, 0);
    }
  }

  // --- epilogue: dwconv 3x3 entirely from LDS + relu -> act_s ---
#pragma unroll
  for (int f = 0; f < 8; ++f) {
    int chl = f * 16 + li;
    float wv[9];
#pragma unroll
    for (int j = 0; j < 9; ++j) wv[j] = wv_s[chl * 9 + j];
    float vb = vb_s[chl];
#pragma unroll
    for (int r = 0; r < 2; ++r) {
      int nbase = nw + r * 16;          // y = nbase/16, x = qd*4..qd*4+3
      int y = nbase >> 4;
      float vv[3][6];
#pragma unroll
      for (int yy = 0; yy < 3; ++yy) {
        int y3 = y - 1 + yy;
#pragma unroll
        for (int c = 0; c < 6; ++c) {
          int x = qd * 4 - 1 + c;
          vv[yy][c] = (y3 >= 0 && y3 < 16 && x >= 0 && x < 16)
                      ? __bfloat162float(v_s[chl][vswz(chl, y3 * 16 + x)]) : 0.f;
        }
      }
#pragma unroll
      for (int rr = 0; rr < 4; ++rr) {
        float s = vb;
#pragma unroll
        for (int yy = 0; yy < 3; ++yy)
#pragma unroll
          for (int j = 0; j < 3; ++j)
            s += vv[yy][rr + j] * wv[yy * 3 + j];
        float v = fmaxf(acc[r][f][rr] + s, 0.f);
        act_s[nbase + qd * 4 + rr][chl] = __float2bfloat16(v);
      }
    }
  }
  __syncthreads();
  // coalesced act write: rows of 256 B (128 ch x bf16)
  for (int it = t; it < 4096; it += 512) {
    int row = it >> 4, seg = it & 15;
    bf16v8 vv = *(const bf16v8*)&act_s[row][seg * 8];
    *(bf16v8*)(act + ((size_t)b * NTOK + row) * DH + h * DHEAD + seg * 8) = vv;
  }
}

// ---------------- K4: proj GEMM out[b,dim,tok] = wp @ act^T + proj_b ----------------
__global__ __launch_bounds__(256, 4) void k_proj(const bf16* __restrict__ act,
    const bf16* __restrict__ proj_w, const float* __restrict__ proj_b,
    int b_base, int nb, float* __restrict__ out) {
  int id = blockIdx.x;
  int b, mt;
  if ((nb & 7) == 0) {
    int per = nb >> 3;
    int xcd = id & 7, slot = id >> 3;
    b = xcd * per + (slot % per);
    mt = slot / per;            // [0,6)
  } else { b = id / 6; mt = id % 6; }
  int m0 = mt * 64;
  int bg = b_base + b;
  int wave = threadIdx.x >> 6, lane = threadIdx.x & 63;
  int qd = lane >> 4, li = lane & 15;
  int n0 = wave * 64;
  f32x4 acc[4][4];
#pragma unroll
  for (int r = 0; r < 4; ++r)
#pragma unroll
    for (int f = 0; f < 4; ++f) acc[r][f] = (f32x4){0.f, 0.f, 0.f, 0.f};
  for (int k0 = 0; k0 < DH; k0 += 32) {
    bf16v8 Af[4], Bf[4];
#pragma unroll
    for (int r = 0; r < 4; ++r)
      Af[r] = *(const bf16v8*)(proj_w + (size_t)(m0 + r * 16 + li) * DH + k0 + qd * 8);
#pragma unroll
    for (int f = 0; f < 4; ++f)
      Bf[f] = *(const bf16v8*)(act + ((size_t)b * NTOK + n0 + f * 16 + li) * DH + k0 + qd * 8);
#pragma unroll
    for (int r = 0; r < 4; ++r)
#pragma unroll
      for (int f = 0; f < 4; ++f)
        acc[r][f] = __builtin_amdgcn_mfma_f32_16x16x32_bf16(Af[r], Bf[f], acc[r][f], 0, 0, 0);
  }
#pragma unroll
  for (int r = 0; r < 4; ++r)
#pragma unroll
    for (int f = 0; f < 4; ++f) {
      int n = n0 + f * 16 + li;
#pragma unroll
      for (int rr = 0; rr < 4; ++rr) {
        int dim = m0 + r * 16 + qd * 4 + rr;
        out[((size_t)bg * DIM + dim) * NTOK + n] = acc[r][f][rr] + sf(proj_b[dim]);
      }
    }
}

extern "C" void kernel_launch(void* const* d_in, const int* in_sizes, int n_in,
                              void* d_out, int out_size, void* d_ws, size_t ws_size,
                              hipStream_t stream) {
  const float* x      = (const float*)d_in[0];
  const float* q_w    = (const float*)d_in[1];
  const float* q_b    = (const float*)d_in[2];
  const float* k_w    = (const float*)d_in[3];
  const float* k_b    = (const float*)d_in[4];
  const float* v_w    = (const float*)d_in[5];
  const float* v_b    = (const float*)d_in[6];
  const float* vl_w   = (const float*)d_in[7];
  const float* vl_b   = (const float*)d_in[8];
  const float* th1_w  = (const float*)d_in[9];
  const float* th1_b  = (const float*)d_in[10];
  const float* th2_w  = (const float*)d_in[11];
  const float* th2_b  = (const float*)d_in[12];
  const float* proj_w = (const float*)d_in[13];
  const float* proj_b = (const float*)d_in[14];
  const float* attn_b = (const float*)d_in[15];
  const int*   idxs   = (const int*)d_in[16];
  int n_off = in_sizes[15] / NH;
  float* out = (float*)d_out;

  const size_t WQ = 98304, WK = 98304, WV = 393216, WP = 393216;
  const size_t WTOT = WQ + WK + WV + WP;                       // 983040 elem
  const size_t BFULL = (size_t)NH * NTOK * NTOK;               // 524288 f32
  const size_t PB_XT = (size_t)NTOK * DIM;                     // 98304
  const size_t PB_QK = (size_t)NH * NTOK * KD;                 // 65536
  const size_t PB_V  = (size_t)DH * NTOK;                      // 262144
  const size_t PB_AC = (size_t)NTOK * DH;                      // 262144
  const size_t PB_P  = (size_t)NH * NTOK * NTOK;               // 524288
  const size_t perb  = (PB_XT + 2 * PB_QK + PB_V + PB_AC + PB_P) * 2;  // 2555904 B
  const size_t fixed = WTOT * 2 + BFULL * 4;

  char* w = (char*)d_ws;
  bf16* wcvt = (bf16*)w;  w += WTOT * 2;
  bf16* wq = wcvt;
  bf16* wk = wcvt + WQ;
  bf16* wv = wcvt + WQ + WK;
  bf16* wp = wcvt + WQ + WK + WV;
  float* bias_full = (float*)w;  w += BFULL * 4;

  size_t rem = (ws_size > fixed) ? (ws_size - fixed) : 0;
  int CH = (int)(rem / perb);
  if (CH > BB) CH = BB;
  if (CH >= 8) CH &= ~7;      // multiple of 8 -> XCD swizzle active
  if (CH < 1) CH = 1;

  bf16* xT  = (bf16*)w;  w += (size_t)CH * PB_XT * 2;
  bf16* qT  = (bf16*)w;  w += (size_t)CH * PB_QK * 2;
  bf16* kT  = (bf16*)w;  w += (size_t)CH * PB_QK * 2;
  bf16* v4  = (bf16*)w;  w += (size_t)CH * PB_V * 2;
  bf16* act = (bf16*)w;  w += (size_t)CH * PB_AC * 2;
  bf16* P   = (bf16*)w;  w += (size_t)CH * PB_P * 2;

  k_convert<<<(int)(WTOT / 256), 256, 0, stream>>>(q_w, k_w, v_w, proj_w, wcvt);
  k_bias<<<256, 256, 0, stream>>>(attn_b, idxs, n_off, th1_w, th1_b, bias_full);

  for (int c0 = 0; c0 < BB; c0 += CH) {
    int cb = (BB - c0 < CH) ? (BB - c0) : CH;
    k_transpose_x<<<dim3(12, 8, cb), 256, 0, stream>>>(x + (size_t)c0 * DIM * NTOK, xT);
    k_qkv<<<cb * 24, 256, 0, stream>>>(xT, wcvt, q_b, k_b, v_b, qT, kT, v4, cb);
    k_scores<<<cb * 16, 512, 0, stream>>>(qT, kT, bias_full,
                                          th1_w, th2_w, th2_b, P, cb);
    k_pv<<<cb * 16 / 2, 512, 0, stream>>>(P, v4, vl_w, vl_b, act, cb);
    k_proj<<<cb * 6, 256, 0, stream>>>(act, wp, proj_b, c0, cb, out);
  }
}

// Round 4
// 545.258 us; speedup vs baseline: 1.0283x; 1.0283x over previous
//
#include <hip/hip_runtime.h>
#include <hip/hip_bf16.h>

typedef __hip_bfloat16 bf16;
typedef __bf16 bf16v8 __attribute__((ext_vector_type(8)));
typedef float f32x4 __attribute__((ext_vector_type(4)));

#define BB    128
#define DIM   384
#define NTOK  256
#define NH    8
#define KD    32
#define DHEAD 128
#define DH    1024
#define SCALE 0.17677669529663687f

// sanitize boundary reads: NaN->0, clamp huge
static __device__ __forceinline__ float sf(float x) {
  return (x == x) ? fminf(fmaxf(x, -1e4f), 1e4f) : 0.f;
}

static __device__ __forceinline__ float rfl(float x) {
  return __int_as_float(__builtin_amdgcn_readfirstlane(__float_as_int(x)));
}

#define GLOAD_LDS16(gsrc, ldst)                                                \
  __builtin_amdgcn_global_load_lds(                                            \
      (const __attribute__((address_space(1))) void*)(gsrc),                   \
      (__attribute__((address_space(3))) void*)(ldst), 16, 0, 0)

// ---------------- K-1a: fp32 weights -> bf16 copies in ws ----------------
__global__ __launch_bounds__(256) void k_convert(const float* __restrict__ qw,
    const float* __restrict__ kw, const float* __restrict__ vw,
    const float* __restrict__ pw, bf16* __restrict__ dst) {
  int i = blockIdx.x * 256 + threadIdx.x;
  float v;
  if (i < 98304)       v = qw[i];
  else if (i < 196608) v = kw[i - 98304];
  else if (i < 589824) v = vw[i - 196608];
  else                 v = pw[i - 589824];
  dst[i] = __float2bfloat16(sf(v));
}

// ---------------- K-1b: bmix[g][n][m] = th1_b[g] + sum_h th1[g][h]*bias[h][idxs[n][m]] ----------------
// TH1's bias path folded in (batch-independent).
__global__ __launch_bounds__(256) void k_bias(const float* __restrict__ ab,
    const int* __restrict__ idxs, int n_off,
    const float* __restrict__ th1_w, const float* __restrict__ th1_b,
    float* __restrict__ bias_full) {
  int nm = blockIdx.x * 256 + threadIdx.x;   // 65536 positions
  int idx = idxs[nm];
  float bh[8];
#pragma unroll
  for (int h = 0; h < 8; ++h) bh[h] = sf(ab[h * n_off + idx]);
#pragma unroll
  for (int g = 0; g < 8; ++g) {
    float a = sf(th1_b[g]);
#pragma unroll
    for (int h = 0; h < 8; ++h) a += sf(th1_w[g * 8 + h]) * bh[h];
    bias_full[(size_t)g * 65536 + nm] = a;
  }
}

// ---------------- K0: x fp32 [cb,384,256] -> xT bf16 [cb,256,384] ----------------
__global__ __launch_bounds__(256) void k_transpose_x(const float* __restrict__ x,
                                                     bf16* __restrict__ xT) {
  __shared__ bf16 tile[32][33];
  int b = blockIdx.z;
  int c0 = blockIdx.x * 32;
  int n0 = blockIdx.y * 32;
  int t = threadIdx.x;
  int tn = t & 31, tc = t >> 5;
#pragma unroll
  for (int p = 0; p < 4; ++p)
    tile[tc + p * 8][tn] =
        __float2bfloat16(sf(x[((size_t)b * DIM + c0 + tc + p * 8) * NTOK + n0 + tn]));
  __syncthreads();
  int wc = t & 31, wn = t >> 5;
#pragma unroll
  for (int p = 0; p < 4; ++p)
    xT[((size_t)b * NTOK + n0 + wn + p * 8) * DIM + c0 + wc] = tile[wc][wn + p * 8];
}

// ---------------- K1: QKV GEMM, LDS-staged m97-style ----------------
__global__ __launch_bounds__(256, 3) void k_qkv(const bf16* __restrict__ xT,
    const bf16* __restrict__ W, const float* __restrict__ q_b,
    const float* __restrict__ k_b, const float* __restrict__ v_b,
    bf16* __restrict__ qT, bf16* __restrict__ kT, bf16* __restrict__ v4,
    int nb) {
  __shared__ __align__(16) char smem[34816];   // stage A16K+B16K | v-epilogue tile 128x136 bf16
  bf16* sA = (bf16*)smem;                      // [128][64]
  bf16* sB = (bf16*)(smem + 16384);            // [128][64]
  bf16* actt = (bf16*)smem;                    // [128][136]

  int id = blockIdx.x;
  int b, tile;
  if ((nb & 7) == 0) {
    int per = nb >> 3;
    int xcd = id & 7, slot = id >> 3;
    b = xcd * per + (slot % per);
    tile = slot / per;          // [0,24)
  } else { b = id / 24; tile = id % 24; }
  int mt = tile >> 1, nt = tile & 1;
  int m0 = mt * 128, n0b = nt * 128;
  int t = threadIdx.x;
  int wave = t >> 6, lane = t & 63;
  int wm = wave >> 1, wn = wave & 1;
  int qd = lane >> 4, li = lane & 15;
  const bf16* xTb = xT + ((size_t)b * NTOK + n0b) * DIM;

  f32x4 acc[4][4];
#pragma unroll
  for (int r = 0; r < 4; ++r)
#pragma unroll
    for (int f = 0; f < 4; ++f) acc[r][f] = (f32x4){0.f, 0.f, 0.f, 0.f};

  for (int ks = 0; ks < 6; ++ks) {
    int k0 = ks * 64;
    __syncthreads();            // prev compute done -> safe to overwrite LDS
#pragma unroll
    for (int i = 0; i < 8; ++i) {
      int g = wave * 512 + i * 64 + lane;      // [0,2048) granules; <1024 -> A
      int gg = g & 1023;
      int row = gg >> 3, slot = gg & 7;
      int col = ((slot ^ (row & 7)) << 3) + k0;
      const bf16* src = (g < 1024)
          ? (W + (size_t)(m0 + row) * DIM + col)
          : (xTb + (size_t)row * DIM + col);
      GLOAD_LDS16(src, smem + (size_t)(wave * 512 + i * 64) * 16);
    }
    __syncthreads();            // staging drained (vmcnt(0) at barrier)
#pragma unroll
    for (int s = 0; s < 2; ++s) {
      bf16v8 Afr[4], Bfr[4];
#pragma unroll
      for (int r = 0; r < 4; ++r) {
        int row = wm * 64 + r * 16 + li;
        Afr[r] = *(const bf16v8*)(sA + row * 64 + (((s * 4 + qd) ^ (row & 7)) << 3));
      }
#pragma unroll
      for (int f = 0; f < 4; ++f) {
        int row = wn * 64 + f * 16 + li;
        Bfr[f] = *(const bf16v8*)(sB + row * 64 + (((s * 4 + qd) ^ (row & 7)) << 3));
      }
#pragma unroll
      for (int r = 0; r < 4; ++r)
#pragma unroll
        for (int f = 0; f < 4; ++f)
          acc[r][f] = __builtin_amdgcn_mfma_f32_16x16x32_bf16(Afr[r], Bfr[f], acc[r][f], 0, 0, 0);
    }
  }
  __syncthreads();              // all LDS reads done before smem reuse

  if (m0 >= 512) {
    // ---- v rows: restage through LDS -> coalesced 16B stores to v4[ch][tok] ----
    int ch0 = m0 - 512;
#pragma unroll
    for (int r = 0; r < 4; ++r)
#pragma unroll
      for (int f = 0; f < 4; ++f) {
        int coll = wn * 64 + f * 16 + li;
#pragma unroll
        for (int rr = 0; rr < 4; ++rr) {
          int rowl = wm * 64 + r * 16 + qd * 4 + rr;
          actt[rowl * 136 + coll] =
              __float2bfloat16(acc[r][f][rr] + sf(v_b[ch0 + rowl]));
        }
      }
    __syncthreads();
#pragma unroll
    for (int it = 0; it < 8; ++it) {
      int g = it * 256 + t;
      int row = g >> 4, c16 = g & 15;
      bf16v8 vv = *(const bf16v8*)(actt + row * 136 + c16 * 8);
      *(bf16v8*)(v4 + ((size_t)b * DH + ch0 + row) * NTOK + n0b + c16 * 8) = vv;
    }
  } else {
    // ---- q/k rows: packed 8B stores (4 consecutive kd per thread) ----
    const float* bias = (m0 < 256) ? q_b : k_b;
    bf16* dst = (m0 < 256) ? qT : kT;
    int mb = (m0 < 256) ? m0 : m0 - 256;
#pragma unroll
    for (int r = 0; r < 4; ++r)
#pragma unroll
      for (int f = 0; f < 4; ++f) {
        int n = n0b + wn * 64 + f * 16 + li;
        int rowg = mb + wm * 64 + r * 16 + qd * 4;
        int h = rowg >> 5, kd = rowg & 31;
        union { bf16 e[4]; uint2 u; } pk;
#pragma unroll
        for (int rr = 0; rr < 4; ++rr)
          pk.e[rr] = __float2bfloat16(acc[r][f][rr] + sf(bias[rowg + rr]));
        *(uint2*)(dst + (((size_t)b * NH + h) * NTOK + n) * KD + kd) = pk.u;
      }
  }
}

// ---------------- K2: scores + TH1(folded bias) + softmax + TH2 -> P ----------------
// RESTRUCTURED: 1024 threads / 16 waves per block; each wave owns a 16-m slice.
// Per-thread serial state halves (S: 32 f32, TH mixes 256+256 FMA, 32 exp) ->
// shorter critical path, 2 blocks/CU (32 waves) residency.
__global__ __launch_bounds__(1024, 8) void k_scores(const bf16* __restrict__ qT,
    const bf16* __restrict__ kT, const float* __restrict__ bias_full,
    const float* __restrict__ th1_w,
    const float* __restrict__ th2_w, const float* __restrict__ th2_b,
    bf16* __restrict__ P, int nb) {
  __shared__ bf16 stage[4][8][16][32];   // 32 KB per round: [g2][mb][nl][m32]
  __shared__ float s_th1[64], s_th2[64], s_t2b[8];
  __shared__ float s_part[16][8][16];    // 8 KB
  __shared__ float s_invl[8][16];
  int t = threadIdx.x;
  // prescale TH1 weights by SCALE (bias path already folded into bias_full)
  if (t < 64) { s_th1[t] = sf(th1_w[t]) * SCALE; s_th2[t] = sf(th2_w[t]); }
  if (t >= 64 && t < 72) s_t2b[t - 64] = sf(th2_b[t - 64]);
  int id = blockIdx.x;
  int b, nt;
  if ((nb & 7) == 0) {
    int per = nb >> 3;
    int xcd = id & 7, slot = id >> 3;
    b = xcd * per + (slot % per);
    nt = slot / per;            // [0,16)
  } else { b = id >> 4; nt = id & 15; }
  int n0 = nt * 16;
  int wave = t >> 6, lane = t & 63, qd = lane >> 4, li = lane & 15;
  int ms = wave * 16;           // 16-m slice per wave

  // ---- QK^T: S[h][r] at (n = n0+qd*4+r, m = ms+li) ----
  f32x4 S[8];
#pragma unroll
  for (int h = 0; h < 8; ++h) {
    bf16v8 Af = *(const bf16v8*)(qT + (((size_t)b * NH + h) * NTOK + n0 + li) * KD + qd * 8);
    bf16v8 Bf = *(const bf16v8*)(kT + (((size_t)b * NH + h) * NTOK + ms + li) * KD + qd * 8);
    f32x4 c = {0.f, 0.f, 0.f, 0.f};
    S[h] = __builtin_amdgcn_mfma_f32_16x16x32_bf16(Af, Bf, c, 0, 0, 0);
  }
  __syncthreads();   // th weights staged in LDS

  // ---- TH1 (SGPR weights) + premixed bias + exp + in-wave row-sums ----
  {
    float w1[64];
#pragma unroll
    for (int i = 0; i < 64; ++i) w1[i] = rfl(s_th1[i]);
#pragma unroll
    for (int r = 0; r < 4; ++r) {
      float e8[8];
#pragma unroll
      for (int g = 0; g < 8; ++g) {
        float a = bias_full[(size_t)(g * NTOK + n0 + qd * 4 + r) * NTOK + ms + li];
#pragma unroll
        for (int h = 0; h < 8; ++h) a += w1[g * 8 + h] * S[h][r];
        e8[g] = __expf(fminf(a, 30.0f));
      }
      // wave-local partial row sums over this wave's 16 m (li lanes)
#pragma unroll
      for (int g = 0; g < 8; ++g) {
        float v = e8[g];
        v += __shfl_xor(v, 1, 64);
        v += __shfl_xor(v, 2, 64);
        v += __shfl_xor(v, 4, 64);
        v += __shfl_xor(v, 8, 64);
        if (li == 0) s_part[wave][g][qd * 4 + r] = v;
      }
#pragma unroll
      for (int g = 0; g < 8; ++g) S[g][r] = e8[g];
    }
  }
  __syncthreads();
  if (t < 128) {
    int g = t >> 4, n = t & 15;
    float ssum = 0.f;
#pragma unroll
    for (int w2 = 0; w2 < 16; ++w2) ssum += s_part[w2][g][n];
    s_invl[g][n] = 1.0f / ssum;
  }
  __syncthreads();
#pragma unroll
  for (int g = 0; g < 8; ++g)
#pragma unroll
    for (int r = 0; r < 4; ++r)
      S[g][r] *= s_invl[g][qd * 4 + r];

  // ---- TH2 (SGPR weights) + blocked-coalesced P store via LDS restage ----
  {
    float w2[64], b2[8];
#pragma unroll
    for (int i = 0; i < 64; ++i) w2[i] = rfl(s_th2[i]);
#pragma unroll
    for (int i = 0; i < 8; ++i) b2[i] = rfl(s_t2b[i]);
    int mb = wave >> 1, mh = (wave & 1) * 16;
#pragma unroll
    for (int gr = 0; gr < 2; ++gr) {
#pragma unroll
      for (int g2i = 0; g2i < 4; ++g2i) {
        int g2 = gr * 4 + g2i;
#pragma unroll
        for (int r = 0; r < 4; ++r) {
          float a = b2[g2];
#pragma unroll
          for (int g = 0; g < 8; ++g) a += w2[g2 * 8 + g] * S[g][r];
          stage[g2i][mb][qd * 4 + r][mh + li] = __float2bfloat16(a);
        }
      }
      __syncthreads();
#pragma unroll
      for (int p = 0; p < 2; ++p) {
        int s = p * 1024 + t;                // [0,2048) 16B granules
        int g2i = s >> 9, mbs = (s >> 6) & 7, le = s & 63;
        bf16v8 vv = *(const bf16v8*)&stage[g2i][mbs][le >> 2][(le & 3) * 8];
        *(bf16v8*)(P + (size_t)b * NH * 65536 + (size_t)(gr * 4 + g2i) * 65536 +
                   (size_t)nt * 4096 + mbs * 512 + le * 8) = vv;
      }
      __syncthreads();
    }
  }
}

// ---------------- K3: O = P@V + dwconv + relu -> act[b,n,ch] ----------------
static __device__ __forceinline__ int vswz(int ch, int tok) {
  return tok ^ ((ch & 7) << 3);
}

__global__ __launch_bounds__(512, 1) void k_pv(const bf16* __restrict__ P,
    const bf16* __restrict__ v4,
    const float* __restrict__ vl_w, const float* __restrict__ vl_b,
    bf16* __restrict__ act, int nb) {
  __shared__ bf16 v_s[128][256];     // 64 KB, bank-swizzled via vswz()
  __shared__ bf16 act_s[256][136];   // 68 KB (+8 pad)
  __shared__ float wv_s[1152];       // dw weights for this head: 4.5 KB
  __shared__ float vb_s[128];
  int id = blockIdx.x;
  int b, h;
  if ((nb & 7) == 0) {
    int per = nb >> 3;
    int xcd = id & 7, slot = id >> 3;
    b = xcd * per + (slot % per);
    h = slot / per;            // [0,8)
  } else { b = id >> 3; h = id & 7; }
  int t = threadIdx.x;
  int wave = t >> 6, lane = t & 63;
  int qd = lane >> 4, li = lane & 15;
  int nw = wave * 32;                // 32 tokens per wave
  int nwt = wave * 2;                // n-tile base
  const bf16* Pb = P + ((size_t)b * NH + h) * 65536;
  const bf16* Vb = v4 + ((size_t)b * DH + h * DHEAD) * NTOK;

  // --- prefetch ALL P fragments (latency hides under V staging; drained by barrier) ---
  bf16v8 Af[4][2][2];
#pragma unroll
  for (int mi = 0; mi < 4; ++mi)
#pragma unroll
    for (int s = 0; s < 2; ++s)
#pragma unroll
      for (int r = 0; r < 2; ++r)
        Af[mi][s][r] = *(const bf16v8*)(Pb + (size_t)(nwt + r) * 4096 +
                                        (mi * 2 + s) * 512 + li * 32 + qd * 8);

  // --- stage V slab (coalesced 16B, swizzled LDS dest) + dw weights ---
#pragma unroll
  for (int p = 0; p < 8; ++p) {
    int idx = p * 512 + t;             // 16-B granule id, 4096 total
    int ch = idx >> 5, tok = (idx & 31) * 8;
    *(bf16v8*)&v_s[ch][vswz(ch, tok)] = *(const bf16v8*)(Vb + (size_t)ch * NTOK + tok);
  }
  for (int i = t; i < 1152; i += 512) wv_s[i] = sf(vl_w[(size_t)h * DHEAD * 9 + i]);
  if (t < 128) vb_s[t] = sf(vl_b[h * DHEAD + t]);
  __syncthreads();

  // --- PV GEMM: B operand from swizzled LDS ---
  f32x4 acc[2][8];
#pragma unroll
  for (int r = 0; r < 2; ++r)
#pragma unroll
    for (int f = 0; f < 8; ++f) acc[r][f] = (f32x4){0.f, 0.f, 0.f, 0.f};
#pragma unroll
  for (int mi = 0; mi < 4; ++mi) {
    int m0 = mi * 64;
#pragma unroll
    for (int s = 0; s < 2; ++s) {
      bf16v8 Bf[8];
#pragma unroll
      for (int f = 0; f < 8; ++f) {
        int ch = f * 16 + li;
        Bf[f] = *(const bf16v8*)&v_s[ch][vswz(ch, m0 + s * 32 + qd * 8)];
      }
#pragma unroll
      for (int f = 0; f < 8; ++f)
#pragma unroll
        for (int r = 0; r < 2; ++r)
          acc[r][f] = __builtin_amdgcn_mfma_f32_16x16x32_bf16(Af[mi][s][r], Bf[f], acc[r][f], 0, 0, 0);
    }
  }

  // --- epilogue: dwconv 3x3 entirely from LDS + relu -> act_s ---
#pragma unroll
  for (int f = 0; f < 8; ++f) {
    int chl = f * 16 + li;
    float wv[9];
#pragma unroll
    for (int j = 0; j < 9; ++j) wv[j] = wv_s[chl * 9 + j];
    float vb = vb_s[chl];
#pragma unroll
    for (int r = 0; r < 2; ++r) {
      int nbase = nw + r * 16;          // y = nbase/16, x = qd*4..qd*4+3
      int y = nbase >> 4;
      float vv[3][6];
#pragma unroll
      for (int yy = 0; yy < 3; ++yy) {
        int y3 = y - 1 + yy;
#pragma unroll
        for (int c = 0; c < 6; ++c) {
          int x = qd * 4 - 1 + c;
          vv[yy][c] = (y3 >= 0 && y3 < 16 && x >= 0 && x < 16)
                      ? __bfloat162float(v_s[chl][vswz(chl, y3 * 16 + x)]) : 0.f;
        }
      }
#pragma unroll
      for (int rr = 0; rr < 4; ++rr) {
        float s = vb;
#pragma unroll
        for (int yy = 0; yy < 3; ++yy)
#pragma unroll
          for (int j = 0; j < 3; ++j)
            s += vv[yy][rr + j] * wv[yy * 3 + j];
        float v = fmaxf(acc[r][f][rr] + s, 0.f);
        act_s[nbase + qd * 4 + rr][chl] = __float2bfloat16(v);
      }
    }
  }
  __syncthreads();
  // coalesced act write: rows of 256 B (128 ch x bf16)
  for (int it = t; it < 4096; it += 512) {
    int row = it >> 4, seg = it & 15;
    bf16v8 vv = *(const bf16v8*)&act_s[row][seg * 8];
    *(bf16v8*)(act + ((size_t)b * NTOK + row) * DH + h * DHEAD + seg * 8) = vv;
  }
}

// ---------------- K4: proj GEMM out[b,dim,tok] = wp @ act^T + proj_b ----------------
__global__ __launch_bounds__(256, 4) void k_proj(const bf16* __restrict__ act,
    const bf16* __restrict__ proj_w, const float* __restrict__ proj_b,
    int b_base, int nb, float* __restrict__ out) {
  int id = blockIdx.x;
  int b, mt;
  if ((nb & 7) == 0) {
    int per = nb >> 3;
    int xcd = id & 7, slot = id >> 3;
    b = xcd * per + (slot % per);
    mt = slot / per;            // [0,6)
  } else { b = id / 6; mt = id % 6; }
  int m0 = mt * 64;
  int bg = b_base + b;
  int wave = threadIdx.x >> 6, lane = threadIdx.x & 63;
  int qd = lane >> 4, li = lane & 15;
  int n0 = wave * 64;
  f32x4 acc[4][4];
#pragma unroll
  for (int r = 0; r < 4; ++r)
#pragma unroll
    for (int f = 0; f < 4; ++f) acc[r][f] = (f32x4){0.f, 0.f, 0.f, 0.f};
  for (int k0 = 0; k0 < DH; k0 += 32) {
    bf16v8 Af[4], Bf[4];
#pragma unroll
    for (int r = 0; r < 4; ++r)
      Af[r] = *(const bf16v8*)(proj_w + (size_t)(m0 + r * 16 + li) * DH + k0 + qd * 8);
#pragma unroll
    for (int f = 0; f < 4; ++f)
      Bf[f] = *(const bf16v8*)(act + ((size_t)b * NTOK + n0 + f * 16 + li) * DH + k0 + qd * 8);
#pragma unroll
    for (int r = 0; r < 4; ++r)
#pragma unroll
      for (int f = 0; f < 4; ++f)
        acc[r][f] = __builtin_amdgcn_mfma_f32_16x16x32_bf16(Af[r], Bf[f], acc[r][f], 0, 0, 0);
  }
#pragma unroll
  for (int r = 0; r < 4; ++r)
#pragma unroll
    for (int f = 0; f < 4; ++f) {
      int n = n0 + f * 16 + li;
#pragma unroll
      for (int rr = 0; rr < 4; ++rr) {
        int dim = m0 + r * 16 + qd * 4 + rr;
        out[((size_t)bg * DIM + dim) * NTOK + n] = acc[r][f][rr] + sf(proj_b[dim]);
      }
    }
}

extern "C" void kernel_launch(void* const* d_in, const int* in_sizes, int n_in,
                              void* d_out, int out_size, void* d_ws, size_t ws_size,
                              hipStream_t stream) {
  const float* x      = (const float*)d_in[0];
  const float* q_w    = (const float*)d_in[1];
  const float* q_b    = (const float*)d_in[2];
  const float* k_w    = (const float*)d_in[3];
  const float* k_b    = (const float*)d_in[4];
  const float* v_w    = (const float*)d_in[5];
  const float* v_b    = (const float*)d_in[6];
  const float* vl_w   = (const float*)d_in[7];
  const float* vl_b   = (const float*)d_in[8];
  const float* th1_w  = (const float*)d_in[9];
  const float* th1_b  = (const float*)d_in[10];
  const float* th2_w  = (const float*)d_in[11];
  const float* th2_b  = (const float*)d_in[12];
  const float* proj_w = (const float*)d_in[13];
  const float* proj_b = (const float*)d_in[14];
  const float* attn_b = (const float*)d_in[15];
  const int*   idxs   = (const int*)d_in[16];
  int n_off = in_sizes[15] / NH;
  float* out = (float*)d_out;

  const size_t WQ = 98304, WK = 98304, WV = 393216, WP = 393216;
  const size_t WTOT = WQ + WK + WV + WP;                       // 983040 elem
  const size_t BFULL = (size_t)NH * NTOK * NTOK;               // 524288 f32
  const size_t PB_XT = (size_t)NTOK * DIM;                     // 98304
  const size_t PB_QK = (size_t)NH * NTOK * KD;                 // 65536
  const size_t PB_V  = (size_t)DH * NTOK;                      // 262144
  const size_t PB_AC = (size_t)NTOK * DH;                      // 262144
  const size_t PB_P  = (size_t)NH * NTOK * NTOK;               // 524288
  const size_t perb  = (PB_XT + 2 * PB_QK + PB_V + PB_AC + PB_P) * 2;  // 2555904 B
  const size_t fixed = WTOT * 2 + BFULL * 4;

  char* w = (char*)d_ws;
  bf16* wcvt = (bf16*)w;  w += WTOT * 2;
  bf16* wq = wcvt;
  bf16* wk = wcvt + WQ;
  bf16* wv = wcvt + WQ + WK;
  bf16* wp = wcvt + WQ + WK + WV;
  float* bias_full = (float*)w;  w += BFULL * 4;

  size_t rem = (ws_size > fixed) ? (ws_size - fixed) : 0;
  int CH = (int)(rem / perb);
  if (CH > BB) CH = BB;
  if (CH >= 8) CH &= ~7;      // multiple of 8 -> XCD swizzle active
  if (CH < 1) CH = 1;

  bf16* xT  = (bf16*)w;  w += (size_t)CH * PB_XT * 2;
  bf16* qT  = (bf16*)w;  w += (size_t)CH * PB_QK * 2;
  bf16* kT  = (bf16*)w;  w += (size_t)CH * PB_QK * 2;
  bf16* v4  = (bf16*)w;  w += (size_t)CH * PB_V * 2;
  bf16* act = (bf16*)w;  w += (size_t)CH * PB_AC * 2;
  bf16* P   = (bf16*)w;  w += (size_t)CH * PB_P * 2;

  k_convert<<<(int)(WTOT / 256), 256, 0, stream>>>(q_w, k_w, v_w, proj_w, wcvt);
  k_bias<<<256, 256, 0, stream>>>(attn_b, idxs, n_off, th1_w, th1_b, bias_full);

  for (int c0 = 0; c0 < BB; c0 += CH) {
    int cb = (BB - c0 < CH) ? (BB - c0) : CH;
    k_transpose_x<<<dim3(12, 8, cb), 256, 0, stream>>>(x + (size_t)c0 * DIM * NTOK, xT);
    k_qkv<<<cb * 24, 256, 0, stream>>>(xT, wcvt, q_b, k_b, v_b, qT, kT, v4, cb);
    k_scores<<<cb * 16, 1024, 0, stream>>>(qT, kT, bias_full,
                                           th1_w, th2_w, th2_b, P, cb);
    k_pv<<<cb * 16 / 2, 512, 0, stream>>>(P, v4, vl_w, vl_b, act, cb);
    k_proj<<<cb * 6, 256, 0, stream>>>(act, wp, proj_b, c0, cb, out);
  }
}

// Round 5
// 532.487 us; speedup vs baseline: 1.0529x; 1.0240x over previous
//
#include <hip/hip_runtime.h>
#include <hip/hip_bf16.h>

typedef __hip_bfloat16 bf16;
typedef __bf16 bf16v8 __attribute__((ext_vector_type(8)));
typedef float f32x4 __attribute__((ext_vector_type(4)));

#define BB    128
#define DIM   384
#define NTOK  256
#define NH    8
#define KD    32
#define DHEAD 128
#define DH    1024
#define SCALE 0.17677669529663687f
#define LOG2E 1.4426950408889634f

// sanitize boundary reads: NaN->0, clamp huge
static __device__ __forceinline__ float sf(float x) {
  return (x == x) ? fminf(fmaxf(x, -1e4f), 1e4f) : 0.f;
}

static __device__ __forceinline__ float rfl(float x) {
  return __int_as_float(__builtin_amdgcn_readfirstlane(__float_as_int(x)));
}

#define GLOAD_LDS16(gsrc, ldst)                                                \
  __builtin_amdgcn_global_load_lds(                                            \
      (const __attribute__((address_space(1))) void*)(gsrc),                   \
      (__attribute__((address_space(3))) void*)(ldst), 16, 0, 0)

// ---------------- K-1a: fp32 weights -> bf16 copies in ws ----------------
__global__ __launch_bounds__(256) void k_convert(const float* __restrict__ qw,
    const float* __restrict__ kw, const float* __restrict__ vw,
    const float* __restrict__ pw, bf16* __restrict__ dst) {
  int i = blockIdx.x * 256 + threadIdx.x;
  float v;
  if (i < 98304)       v = qw[i];
  else if (i < 196608) v = kw[i - 98304];
  else if (i < 589824) v = vw[i - 196608];
  else                 v = pw[i - 589824];
  dst[i] = __float2bfloat16(sf(v));
}

// ---------------- K-1b: bias premix, TRANSPOSED layout [g][m][n], log2e-folded ----------------
// bmix[g][m][n] = LOG2E * (th1_b[g] + sum_h th1[g][h]*bias[h][idxs[n][m]])
__global__ __launch_bounds__(256) void k_bias(const float* __restrict__ ab,
    const int* __restrict__ idxs, int n_off,
    const float* __restrict__ th1_w, const float* __restrict__ th1_b,
    float* __restrict__ bias_full) {
  int mn = blockIdx.x * 256 + threadIdx.x;   // m-major for coalesced writes
  int m = mn >> 8, n = mn & 255;
  int idx = idxs[n * 256 + m];
  float bh[8];
#pragma unroll
  for (int h = 0; h < 8; ++h) bh[h] = sf(ab[h * n_off + idx]);
#pragma unroll
  for (int g = 0; g < 8; ++g) {
    float a = sf(th1_b[g]);
#pragma unroll
    for (int h = 0; h < 8; ++h) a += sf(th1_w[g * 8 + h]) * bh[h];
    bias_full[((size_t)g * 256 + m) * 256 + n] = a * LOG2E;
  }
}

// ---------------- K0: x fp32 [cb,384,256] -> xT bf16 [cb,256,384] ----------------
__global__ __launch_bounds__(256) void k_transpose_x(const float* __restrict__ x,
                                                     bf16* __restrict__ xT) {
  __shared__ bf16 tile[32][33];
  int b = blockIdx.z;
  int c0 = blockIdx.x * 32;
  int n0 = blockIdx.y * 32;
  int t = threadIdx.x;
  int tn = t & 31, tc = t >> 5;
#pragma unroll
  for (int p = 0; p < 4; ++p)
    tile[tc + p * 8][tn] =
        __float2bfloat16(sf(x[((size_t)b * DIM + c0 + tc + p * 8) * NTOK + n0 + tn]));
  __syncthreads();
  int wc = t & 31, wn = t >> 5;
#pragma unroll
  for (int p = 0; p < 4; ++p)
    xT[((size_t)b * NTOK + n0 + wn + p * 8) * DIM + c0 + wc] = tile[wc][wn + p * 8];
}

// ---------------- K1: QKV GEMM, LDS-staged m97-style ----------------
__global__ __launch_bounds__(256, 3) void k_qkv(const bf16* __restrict__ xT,
    const bf16* __restrict__ W, const float* __restrict__ q_b,
    const float* __restrict__ k_b, const float* __restrict__ v_b,
    bf16* __restrict__ qT, bf16* __restrict__ kT, bf16* __restrict__ v4,
    int nb) {
  __shared__ __align__(16) char smem[34816];   // stage A16K+B16K | v-epilogue tile 128x136 bf16
  bf16* sA = (bf16*)smem;                      // [128][64]
  bf16* sB = (bf16*)(smem + 16384);            // [128][64]
  bf16* actt = (bf16*)smem;                    // [128][136]

  int id = blockIdx.x;
  int b, tile;
  if ((nb & 7) == 0) {
    int per = nb >> 3;
    int xcd = id & 7, slot = id >> 3;
    b = xcd * per + (slot % per);
    tile = slot / per;          // [0,24)
  } else { b = id / 24; tile = id % 24; }
  int mt = tile >> 1, nt = tile & 1;
  int m0 = mt * 128, n0b = nt * 128;
  int t = threadIdx.x;
  int wave = t >> 6, lane = t & 63;
  int wm = wave >> 1, wn = wave & 1;
  int qd = lane >> 4, li = lane & 15;
  const bf16* xTb = xT + ((size_t)b * NTOK + n0b) * DIM;

  f32x4 acc[4][4];
#pragma unroll
  for (int r = 0; r < 4; ++r)
#pragma unroll
    for (int f = 0; f < 4; ++f) acc[r][f] = (f32x4){0.f, 0.f, 0.f, 0.f};

  for (int ks = 0; ks < 6; ++ks) {
    int k0 = ks * 64;
    __syncthreads();            // prev compute done -> safe to overwrite LDS
#pragma unroll
    for (int i = 0; i < 8; ++i) {
      int g = wave * 512 + i * 64 + lane;      // [0,2048) granules; <1024 -> A
      int gg = g & 1023;
      int row = gg >> 3, slot = gg & 7;
      int col = ((slot ^ (row & 7)) << 3) + k0;
      const bf16* src = (g < 1024)
          ? (W + (size_t)(m0 + row) * DIM + col)
          : (xTb + (size_t)row * DIM + col);
      GLOAD_LDS16(src, smem + (size_t)(wave * 512 + i * 64) * 16);
    }
    __syncthreads();            // staging drained (vmcnt(0) at barrier)
#pragma unroll
    for (int s = 0; s < 2; ++s) {
      bf16v8 Afr[4], Bfr[4];
#pragma unroll
      for (int r = 0; r < 4; ++r) {
        int row = wm * 64 + r * 16 + li;
        Afr[r] = *(const bf16v8*)(sA + row * 64 + (((s * 4 + qd) ^ (row & 7)) << 3));
      }
#pragma unroll
      for (int f = 0; f < 4; ++f) {
        int row = wn * 64 + f * 16 + li;
        Bfr[f] = *(const bf16v8*)(sB + row * 64 + (((s * 4 + qd) ^ (row & 7)) << 3));
      }
#pragma unroll
      for (int r = 0; r < 4; ++r)
#pragma unroll
        for (int f = 0; f < 4; ++f)
          acc[r][f] = __builtin_amdgcn_mfma_f32_16x16x32_bf16(Afr[r], Bfr[f], acc[r][f], 0, 0, 0);
    }
  }
  __syncthreads();              // all LDS reads done before smem reuse

  if (m0 >= 512) {
    // ---- v rows: restage through LDS -> coalesced 16B stores to v4[ch][tok] ----
    int ch0 = m0 - 512;
#pragma unroll
    for (int r = 0; r < 4; ++r)
#pragma unroll
      for (int f = 0; f < 4; ++f) {
        int coll = wn * 64 + f * 16 + li;
#pragma unroll
        for (int rr = 0; rr < 4; ++rr) {
          int rowl = wm * 64 + r * 16 + qd * 4 + rr;
          actt[rowl * 136 + coll] =
              __float2bfloat16(acc[r][f][rr] + sf(v_b[ch0 + rowl]));
        }
      }
    __syncthreads();
#pragma unroll
    for (int it = 0; it < 8; ++it) {
      int g = it * 256 + t;
      int row = g >> 4, c16 = g & 15;
      bf16v8 vv = *(const bf16v8*)(actt + row * 136 + c16 * 8);
      *(bf16v8*)(v4 + ((size_t)b * DH + ch0 + row) * NTOK + n0b + c16 * 8) = vv;
    }
  } else {
    // ---- q/k rows: packed 8B stores (4 consecutive kd per thread) ----
    const float* bias = (m0 < 256) ? q_b : k_b;
    bf16* dst = (m0 < 256) ? qT : kT;
    int mb = (m0 < 256) ? m0 : m0 - 256;
#pragma unroll
    for (int r = 0; r < 4; ++r)
#pragma unroll
      for (int f = 0; f < 4; ++f) {
        int n = n0b + wn * 64 + f * 16 + li;
        int rowg = mb + wm * 64 + r * 16 + qd * 4;
        int h = rowg >> 5, kd = rowg & 31;
        union { bf16 e[4]; uint2 u; } pk;
#pragma unroll
        for (int rr = 0; rr < 4; ++rr)
          pk.e[rr] = __float2bfloat16(acc[r][f][rr] + sf(bias[rowg + rr]));
        *(uint2*)(dst + (((size_t)b * NH + h) * NTOK + n) * KD + kd) = pk.u;
      }
  }
}

// ---------------- K2: scores, SWAPPED-operand QK^T (m in regs, n in lanes) ----------------
// mfma(K,Q): D[m-row][n-col]. Thread holds 4 consecutive m per (g,r-reg) -> row-sum is
// 3 adds + 2 shfl per g; TH2 output packs to one 8B store per g2 (no LDS restage).
__global__ __launch_bounds__(1024, 4) void k_scores(const bf16* __restrict__ qT,
    const bf16* __restrict__ kT, const float* __restrict__ bias_full,
    const float* __restrict__ th1_w,
    const float* __restrict__ th2_w, const float* __restrict__ th2_b,
    bf16* __restrict__ P, int nb) {
  __shared__ float s_th1[64], s_th2[64], s_t2b[8];
  __shared__ float s_part[16][8][16];    // 8 KB
  __shared__ float s_invl[8][16];
  int t = threadIdx.x;
  // fold SCALE*log2e into TH1 weights (bias premix already *log2e)
  if (t < 64) { s_th1[t] = sf(th1_w[t]) * (SCALE * LOG2E); s_th2[t] = sf(th2_w[t]); }
  if (t >= 64 && t < 72) s_t2b[t - 64] = sf(th2_b[t - 64]);
  int id = blockIdx.x;
  int b, nt;
  if ((nb & 7) == 0) {
    int per = nb >> 3;
    int xcd = id & 7, slot = id >> 3;
    b = xcd * per + (slot % per);
    nt = slot / per;            // [0,16)
  } else { b = id >> 4; nt = id & 15; }
  int n0 = nt * 16;
  int wave = t >> 6, lane = t & 63, qd = lane >> 4, li = lane & 15;
  int ms = wave * 16;           // this wave's 16-m slice

  // ---- QK^T swapped: S[h][r] at (m = ms+qd*4+r, n = n0+li) ----
  f32x4 S[8];
#pragma unroll
  for (int h = 0; h < 8; ++h) {
    bf16v8 Ak = *(const bf16v8*)(kT + (((size_t)b * NH + h) * NTOK + ms + li) * KD + qd * 8);
    bf16v8 Bq = *(const bf16v8*)(qT + (((size_t)b * NH + h) * NTOK + n0 + li) * KD + qd * 8);
    f32x4 c = {0.f, 0.f, 0.f, 0.f};
    S[h] = __builtin_amdgcn_mfma_f32_16x16x32_bf16(Ak, Bq, c, 0, 0, 0);
  }
  __syncthreads();   // th weights staged in LDS

  // ---- TH1 (SGPR weights) + premixed bias + exp2 ----
  f32x4 E[8];
  {
    float w1[64];
#pragma unroll
    for (int i = 0; i < 64; ++i) w1[i] = rfl(s_th1[i]);
#pragma unroll
    for (int r = 0; r < 4; ++r) {
#pragma unroll
      for (int g = 0; g < 8; ++g) {
        float a = bias_full[((size_t)g * 256 + ms + qd * 4 + r) * 256 + n0 + li];
#pragma unroll
        for (int h = 0; h < 8; ++h) a += w1[g * 8 + h] * S[h][r];
        E[g][r] = exp2f(fminf(a, 43.3f));
      }
    }
  }
  // ---- row sums: 3 in-thread adds + 2 shfl per g ----
#pragma unroll
  for (int g = 0; g < 8; ++g) {
    float v = (E[g][0] + E[g][1]) + (E[g][2] + E[g][3]);
    v += __shfl_xor(v, 16, 64);
    v += __shfl_xor(v, 32, 64);
    if (qd == 0) s_part[wave][g][li] = v;
  }
  __syncthreads();
  if (t < 128) {
    int g = t >> 4, n = t & 15;
    float ssum = 0.f;
#pragma unroll
    for (int w2 = 0; w2 < 16; ++w2) ssum += s_part[w2][g][n];
    s_invl[g][n] = 1.0f / ssum;
  }
  __syncthreads();
#pragma unroll
  for (int g = 0; g < 8; ++g) {
    float inv = s_invl[g][li];
#pragma unroll
    for (int r = 0; r < 4; ++r) E[g][r] *= inv;
  }

  // ---- TH2 (SGPR weights) + direct packed 8B P store (blocked layout unchanged) ----
  {
    float w2[64], b2[8];
#pragma unroll
    for (int i = 0; i < 64; ++i) w2[i] = rfl(s_th2[i]);
#pragma unroll
    for (int i = 0; i < 8; ++i) b2[i] = rfl(s_t2b[i]);
    size_t pbase = (size_t)b * NH * 65536 + (size_t)nt * 4096 +
                   (size_t)(wave >> 1) * 512 + li * 32 + (wave & 1) * 16 + qd * 4;
#pragma unroll
    for (int g2 = 0; g2 < 8; ++g2) {
      union { bf16 e[4]; uint2 u; } pk;
#pragma unroll
      for (int r = 0; r < 4; ++r) {
        float a = b2[g2];
#pragma unroll
        for (int g = 0; g < 8; ++g) a += w2[g2 * 8 + g] * E[g][r];
        pk.e[r] = __float2bfloat16(a);
      }
      *(uint2*)(P + pbase + (size_t)g2 * 65536) = pk.u;
    }
  }
}

// ---------------- K3: O = P@V + dwconv + relu -> act[b,n,ch] ----------------
static __device__ __forceinline__ int vswz(int ch, int tok) {
  return tok ^ ((ch & 7) << 3);
}

__global__ __launch_bounds__(512, 1) void k_pv(const bf16* __restrict__ P,
    const bf16* __restrict__ v4,
    const float* __restrict__ vl_w, const float* __restrict__ vl_b,
    bf16* __restrict__ act, int nb) {
  __shared__ bf16 v_s[128][256];     // 64 KB, bank-swizzled via vswz()
  __shared__ bf16 act_s[256][136];   // 68 KB (+8 pad)
  __shared__ float wv_s[1152];       // dw weights for this head: 4.5 KB
  __shared__ float vb_s[128];
  int id = blockIdx.x;
  int b, h;
  if ((nb & 7) == 0) {
    int per = nb >> 3;
    int xcd = id & 7, slot = id >> 3;
    b = xcd * per + (slot % per);
    h = slot / per;            // [0,8)
  } else { b = id >> 3; h = id & 7; }
  int t = threadIdx.x;
  int wave = t >> 6, lane = t & 63;
  int qd = lane >> 4, li = lane & 15;
  int nw = wave * 32;                // 32 tokens per wave
  int nwt = wave * 2;                // n-tile base
  const bf16* Pb = P + ((size_t)b * NH + h) * 65536;
  const bf16* Vb = v4 + ((size_t)b * DH + h * DHEAD) * NTOK;

  // --- prefetch ALL P fragments (latency hides under V staging; drained by barrier) ---
  bf16v8 Af[4][2][2];
#pragma unroll
  for (int mi = 0; mi < 4; ++mi)
#pragma unroll
    for (int s = 0; s < 2; ++s)
#pragma unroll
      for (int r = 0; r < 2; ++r)
        Af[mi][s][r] = *(const bf16v8*)(Pb + (size_t)(nwt + r) * 4096 +
                                        (mi * 2 + s) * 512 + li * 32 + qd * 8);

  // --- stage V slab (coalesced 16B, swizzled LDS dest) + dw weights ---
#pragma unroll
  for (int p = 0; p < 8; ++p) {
    int idx = p * 512 + t;             // 16-B granule id, 4096 total
    int ch = idx >> 5, tok = (idx & 31) * 8;
    *(bf16v8*)&v_s[ch][vswz(ch, tok)] = *(const bf16v8*)(Vb + (size_t)ch * NTOK + tok);
  }
  for (int i = t; i < 1152; i += 512) wv_s[i] = sf(vl_w[(size_t)h * DHEAD * 9 + i]);
  if (t < 128) vb_s[t] = sf(vl_b[h * DHEAD + t]);
  __syncthreads();

  // --- PV GEMM: B operand from swizzled LDS ---
  f32x4 acc[2][8];
#pragma unroll
  for (int r = 0; r < 2; ++r)
#pragma unroll
    for (int f = 0; f < 8; ++f) acc[r][f] = (f32x4){0.f, 0.f, 0.f, 0.f};
#pragma unroll
  for (int mi = 0; mi < 4; ++mi) {
    int m0 = mi * 64;
#pragma unroll
    for (int s = 0; s < 2; ++s) {
      bf16v8 Bf[8];
#pragma unroll
      for (int f = 0; f < 8; ++f) {
        int ch = f * 16 + li;
        Bf[f] = *(const bf16v8*)&v_s[ch][vswz(ch, m0 + s * 32 + qd * 8)];
      }
#pragma unroll
      for (int f = 0; f < 8; ++f)
#pragma unroll
        for (int r = 0; r < 2; ++r)
          acc[r][f] = __builtin_amdgcn_mfma_f32_16x16x32_bf16(Af[mi][s][r], Bf[f], acc[r][f], 0, 0, 0);
    }
  }

  // --- epilogue: dwconv 3x3 entirely from LDS + relu -> act_s ---
#pragma unroll
  for (int f = 0; f < 8; ++f) {
    int chl = f * 16 + li;
    float wv[9];
#pragma unroll
    for (int j = 0; j < 9; ++j) wv[j] = wv_s[chl * 9 + j];
    float vb = vb_s[chl];
#pragma unroll
    for (int r = 0; r < 2; ++r) {
      int nbase = nw + r * 16;          // y = nbase/16, x = qd*4..qd*4+3
      int y = nbase >> 4;
      float vv[3][6];
#pragma unroll
      for (int yy = 0; yy < 3; ++yy) {
        int y3 = y - 1 + yy;
#pragma unroll
        for (int c = 0; c < 6; ++c) {
          int x = qd * 4 - 1 + c;
          vv[yy][c] = (y3 >= 0 && y3 < 16 && x >= 0 && x < 16)
                      ? __bfloat162float(v_s[chl][vswz(chl, y3 * 16 + x)]) : 0.f;
        }
      }
#pragma unroll
      for (int rr = 0; rr < 4; ++rr) {
        float s = vb;
#pragma unroll
        for (int yy = 0; yy < 3; ++yy)
#pragma unroll
          for (int j = 0; j < 3; ++j)
            s += vv[yy][rr + j] * wv[yy * 3 + j];
        float v = fmaxf(acc[r][f][rr] + s, 0.f);
        act_s[nbase + qd * 4 + rr][chl] = __float2bfloat16(v);
      }
    }
  }
  __syncthreads();
  // coalesced act write: rows of 256 B (128 ch x bf16)
  for (int it = t; it < 4096; it += 512) {
    int row = it >> 4, seg = it & 15;
    bf16v8 vv = *(const bf16v8*)&act_s[row][seg * 8];
    *(bf16v8*)(act + ((size_t)b * NTOK + row) * DH + h * DHEAD + seg * 8) = vv;
  }
}

// ---------------- K4: proj GEMM out[b,dim,tok] = wp @ act^T + proj_b ----------------
__global__ __launch_bounds__(256, 4) void k_proj(const bf16* __restrict__ act,
    const bf16* __restrict__ proj_w, const float* __restrict__ proj_b,
    int b_base, int nb, float* __restrict__ out) {
  int id = blockIdx.x;
  int b, mt;
  if ((nb & 7) == 0) {
    int per = nb >> 3;
    int xcd = id & 7, slot = id >> 3;
    b = xcd * per + (slot % per);
    mt = slot / per;            // [0,6)
  } else { b = id / 6; mt = id % 6; }
  int m0 = mt * 64;
  int bg = b_base + b;
  int wave = threadIdx.x >> 6, lane = threadIdx.x & 63;
  int qd = lane >> 4, li = lane & 15;
  int n0 = wave * 64;
  f32x4 acc[4][4];
#pragma unroll
  for (int r = 0; r < 4; ++r)
#pragma unroll
    for (int f = 0; f < 4; ++f) acc[r][f] = (f32x4){0.f, 0.f, 0.f, 0.f};
  for (int k0 = 0; k0 < DH; k0 += 32) {
    bf16v8 Af[4], Bf[4];
#pragma unroll
    for (int r = 0; r < 4; ++r)
      Af[r] = *(const bf16v8*)(proj_w + (size_t)(m0 + r * 16 + li) * DH + k0 + qd * 8);
#pragma unroll
    for (int f = 0; f < 4; ++f)
      Bf[f] = *(const bf16v8*)(act + ((size_t)b * NTOK + n0 + f * 16 + li) * DH + k0 + qd * 8);
#pragma unroll
    for (int r = 0; r < 4; ++r)
#pragma unroll
      for (int f = 0; f < 4; ++f)
        acc[r][f] = __builtin_amdgcn_mfma_f32_16x16x32_bf16(Af[r], Bf[f], acc[r][f], 0, 0, 0);
  }
#pragma unroll
  for (int r = 0; r < 4; ++r)
#pragma unroll
    for (int f = 0; f < 4; ++f) {
      int n = n0 + f * 16 + li;
#pragma unroll
      for (int rr = 0; rr < 4; ++rr) {
        int dim = m0 + r * 16 + qd * 4 + rr;
        out[((size_t)bg * DIM + dim) * NTOK + n] = acc[r][f][rr] + sf(proj_b[dim]);
      }
    }
}

extern "C" void kernel_launch(void* const* d_in, const int* in_sizes, int n_in,
                              void* d_out, int out_size, void* d_ws, size_t ws_size,
                              hipStream_t stream) {
  const float* x      = (const float*)d_in[0];
  const float* q_w    = (const float*)d_in[1];
  const float* q_b    = (const float*)d_in[2];
  const float* k_w    = (const float*)d_in[3];
  const float* k_b    = (const float*)d_in[4];
  const float* v_w    = (const float*)d_in[5];
  const float* v_b    = (const float*)d_in[6];
  const float* vl_w   = (const float*)d_in[7];
  const float* vl_b   = (const float*)d_in[8];
  const float* th1_w  = (const float*)d_in[9];
  const float* th1_b  = (const float*)d_in[10];
  const float* th2_w  = (const float*)d_in[11];
  const float* th2_b  = (const float*)d_in[12];
  const float* proj_w = (const float*)d_in[13];
  const float* proj_b = (const float*)d_in[14];
  const float* attn_b = (const float*)d_in[15];
  const int*   idxs   = (const int*)d_in[16];
  int n_off = in_sizes[15] / NH;
  float* out = (float*)d_out;

  const size_t WQ = 98304, WK = 98304, WV = 393216, WP = 393216;
  const size_t WTOT = WQ + WK + WV + WP;                       // 983040 elem
  const size_t BFULL = (size_t)NH * NTOK * NTOK;               // 524288 f32
  const size_t PB_XT = (size_t)NTOK * DIM;                     // 98304
  const size_t PB_QK = (size_t)NH * NTOK * KD;                 // 65536
  const size_t PB_V  = (size_t)DH * NTOK;                      // 262144
  const size_t PB_AC = (size_t)NTOK * DH;                      // 262144
  const size_t PB_P  = (size_t)NH * NTOK * NTOK;               // 524288
  const size_t perb  = (PB_XT + 2 * PB_QK + PB_V + PB_AC + PB_P) * 2;  // 2555904 B
  const size_t fixed = WTOT * 2 + BFULL * 4;

  char* w = (char*)d_ws;
  bf16* wcvt = (bf16*)w;  w += WTOT * 2;
  bf16* wq = wcvt;
  bf16* wk = wcvt + WQ;
  bf16* wv = wcvt + WQ + WK;
  bf16* wp = wcvt + WQ + WK + WV;
  float* bias_full = (float*)w;  w += BFULL * 4;

  size_t rem = (ws_size > fixed) ? (ws_size - fixed) : 0;
  int CH = (int)(rem / perb);
  if (CH > BB) CH = BB;
  if (CH >= 8) CH &= ~7;      // multiple of 8 -> XCD swizzle active
  if (CH < 1) CH = 1;

  bf16* xT  = (bf16*)w;  w += (size_t)CH * PB_XT * 2;
  bf16* qT  = (bf16*)w;  w += (size_t)CH * PB_QK * 2;
  bf16* kT  = (bf16*)w;  w += (size_t)CH * PB_QK * 2;
  bf16* v4  = (bf16*)w;  w += (size_t)CH * PB_V * 2;
  bf16* act = (bf16*)w;  w += (size_t)CH * PB_AC * 2;
  bf16* P   = (bf16*)w;  w += (size_t)CH * PB_P * 2;

  k_convert<<<(int)(WTOT / 256), 256, 0, stream>>>(q_w, k_w, v_w, proj_w, wcvt);
  k_bias<<<256, 256, 0, stream>>>(attn_b, idxs, n_off, th1_w, th1_b, bias_full);

  for (int c0 = 0; c0 < BB; c0 += CH) {
    int cb = (BB - c0 < CH) ? (BB - c0) : CH;
    k_transpose_x<<<dim3(12, 8, cb), 256, 0, stream>>>(x + (size_t)c0 * DIM * NTOK, xT);
    k_qkv<<<cb * 24, 256, 0, stream>>>(xT, wcvt, q_b, k_b, v_b, qT, kT, v4, cb);
    k_scores<<<cb * 16, 1024, 0, stream>>>(qT, kT, bias_full,
                                           th1_w, th2_w, th2_b, P, cb);
    k_pv<<<cb * 16 / 2, 512, 0, stream>>>(P, v4, vl_w, vl_b, act, cb);
    k_proj<<<cb * 6, 256, 0, stream>>>(act, wp, proj_b, c0, cb, out);
  }
}

// Round 6
// 490.454 us; speedup vs baseline: 1.1432x; 1.0857x over previous
//
#include <hip/hip_runtime.h>
#include <hip/hip_bf16.h>

typedef __hip_bfloat16 bf16;
typedef __bf16 bf16v8 __attribute__((ext_vector_type(8)));
typedef float f32x4 __attribute__((ext_vector_type(4)));

#define BB    128
#define DIM   384
#define NTOK  256
#define NH    8
#define KD    32
#define DHEAD 128
#define DH    1024
#define SCALE 0.17677669529663687f
#define LOG2E 1.4426950408889634f

// sanitize boundary reads: NaN->0, clamp huge
static __device__ __forceinline__ float sf(float x) {
  return (x == x) ? fminf(fmaxf(x, -1e4f), 1e4f) : 0.f;
}

static __device__ __forceinline__ float rfl(float x) {
  return __int_as_float(__builtin_amdgcn_readfirstlane(__float_as_int(x)));
}

#define GLOAD_LDS16(gsrc, ldst)                                                \
  __builtin_amdgcn_global_load_lds(                                            \
      (const __attribute__((address_space(1))) void*)(gsrc),                   \
      (__attribute__((address_space(3))) void*)(ldst), 16, 0, 0)

// ---------------- K-1a: fp32 weights -> bf16 copies in ws ----------------
__global__ __launch_bounds__(256) void k_convert(const float* __restrict__ qw,
    const float* __restrict__ kw, const float* __restrict__ vw,
    const float* __restrict__ pw, bf16* __restrict__ dst) {
  int i = blockIdx.x * 256 + threadIdx.x;
  float v;
  if (i < 98304)       v = qw[i];
  else if (i < 196608) v = kw[i - 98304];
  else if (i < 589824) v = vw[i - 196608];
  else                 v = pw[i - 589824];
  dst[i] = __float2bfloat16(sf(v));
}

// ---------------- K-1b: bias premix, TRANSPOSED layout [g][m][n], log2e-folded ----------------
__global__ __launch_bounds__(256) void k_bias(const float* __restrict__ ab,
    const int* __restrict__ idxs, int n_off,
    const float* __restrict__ th1_w, const float* __restrict__ th1_b,
    float* __restrict__ bias_full) {
  int mn = blockIdx.x * 256 + threadIdx.x;   // m-major for coalesced writes
  int m = mn >> 8, n = mn & 255;
  int idx = idxs[n * 256 + m];
  float bh[8];
#pragma unroll
  for (int h = 0; h < 8; ++h) bh[h] = sf(ab[h * n_off + idx]);
#pragma unroll
  for (int g = 0; g < 8; ++g) {
    float a = sf(th1_b[g]);
#pragma unroll
    for (int h = 0; h < 8; ++h) a += sf(th1_w[g * 8 + h]) * bh[h];
    bias_full[((size_t)g * 256 + m) * 256 + n] = a * LOG2E;
  }
}

// ---------------- K0: x fp32 [cb,384,256] -> xT bf16 [cb,256,384] ----------------
__global__ __launch_bounds__(256) void k_transpose_x(const float* __restrict__ x,
                                                     bf16* __restrict__ xT) {
  __shared__ bf16 tile[32][33];
  int b = blockIdx.z;
  int c0 = blockIdx.x * 32;
  int n0 = blockIdx.y * 32;
  int t = threadIdx.x;
  int tn = t & 31, tc = t >> 5;
#pragma unroll
  for (int p = 0; p < 4; ++p)
    tile[tc + p * 8][tn] =
        __float2bfloat16(sf(x[((size_t)b * DIM + c0 + tc + p * 8) * NTOK + n0 + tn]));
  __syncthreads();
  int wc = t & 31, wn = t >> 5;
#pragma unroll
  for (int p = 0; p < 4; ++p)
    xT[((size_t)b * NTOK + n0 + wn + p * 8) * DIM + c0 + wc] = tile[wc][wn + p * 8];
}

// ---------------- K1: QKV GEMM, LDS-staged m97-style ----------------
__global__ __launch_bounds__(256, 3) void k_qkv(const bf16* __restrict__ xT,
    const bf16* __restrict__ W, const float* __restrict__ q_b,
    const float* __restrict__ k_b, const float* __restrict__ v_b,
    bf16* __restrict__ qT, bf16* __restrict__ kT, bf16* __restrict__ v4,
    int nb) {
  __shared__ __align__(16) char smem[34816];   // stage A16K+B16K | v-epilogue tile 128x136 bf16
  bf16* sA = (bf16*)smem;                      // [128][64]
  bf16* sB = (bf16*)(smem + 16384);            // [128][64]
  bf16* actt = (bf16*)smem;                    // [128][136]

  int id = blockIdx.x;
  int b, tile;
  if ((nb & 7) == 0) {
    int per = nb >> 3;
    int xcd = id & 7, slot = id >> 3;
    b = xcd * per + (slot % per);
    tile = slot / per;          // [0,24)
  } else { b = id / 24; tile = id % 24; }
  int mt = tile >> 1, nt = tile & 1;
  int m0 = mt * 128, n0b = nt * 128;
  int t = threadIdx.x;
  int wave = t >> 6, lane = t & 63;
  int wm = wave >> 1, wn = wave & 1;
  int qd = lane >> 4, li = lane & 15;
  const bf16* xTb = xT + ((size_t)b * NTOK + n0b) * DIM;

  f32x4 acc[4][4];
#pragma unroll
  for (int r = 0; r < 4; ++r)
#pragma unroll
    for (int f = 0; f < 4; ++f) acc[r][f] = (f32x4){0.f, 0.f, 0.f, 0.f};

  for (int ks = 0; ks < 6; ++ks) {
    int k0 = ks * 64;
    __syncthreads();            // prev compute done -> safe to overwrite LDS
#pragma unroll
    for (int i = 0; i < 8; ++i) {
      int g = wave * 512 + i * 64 + lane;      // [0,2048) granules; <1024 -> A
      int gg = g & 1023;
      int row = gg >> 3, slot = gg & 7;
      int col = ((slot ^ (row & 7)) << 3) + k0;
      const bf16* src = (g < 1024)
          ? (W + (size_t)(m0 + row) * DIM + col)
          : (xTb + (size_t)row * DIM + col);
      GLOAD_LDS16(src, smem + (size_t)(wave * 512 + i * 64) * 16);
    }
    __syncthreads();            // staging drained (vmcnt(0) at barrier)
#pragma unroll
    for (int s = 0; s < 2; ++s) {
      bf16v8 Afr[4], Bfr[4];
#pragma unroll
      for (int r = 0; r < 4; ++r) {
        int row = wm * 64 + r * 16 + li;
        Afr[r] = *(const bf16v8*)(sA + row * 64 + (((s * 4 + qd) ^ (row & 7)) << 3));
      }
#pragma unroll
      for (int f = 0; f < 4; ++f) {
        int row = wn * 64 + f * 16 + li;
        Bfr[f] = *(const bf16v8*)(sB + row * 64 + (((s * 4 + qd) ^ (row & 7)) << 3));
      }
#pragma unroll
      for (int r = 0; r < 4; ++r)
#pragma unroll
        for (int f = 0; f < 4; ++f)
          acc[r][f] = __builtin_amdgcn_mfma_f32_16x16x32_bf16(Afr[r], Bfr[f], acc[r][f], 0, 0, 0);
    }
  }
  __syncthreads();              // all LDS reads done before smem reuse

  if (m0 >= 512) {
    // ---- v rows: restage through LDS -> coalesced 16B stores to v4[ch][tok] ----
    int ch0 = m0 - 512;
#pragma unroll
    for (int r = 0; r < 4; ++r)
#pragma unroll
      for (int f = 0; f < 4; ++f) {
        int coll = wn * 64 + f * 16 + li;
#pragma unroll
        for (int rr = 0; rr < 4; ++rr) {
          int rowl = wm * 64 + r * 16 + qd * 4 + rr;
          actt[rowl * 136 + coll] =
              __float2bfloat16(acc[r][f][rr] + sf(v_b[ch0 + rowl]));
        }
      }
    __syncthreads();
#pragma unroll
    for (int it = 0; it < 8; ++it) {
      int g = it * 256 + t;
      int row = g >> 4, c16 = g & 15;
      bf16v8 vv = *(const bf16v8*)(actt + row * 136 + c16 * 8);
      *(bf16v8*)(v4 + ((size_t)b * DH + ch0 + row) * NTOK + n0b + c16 * 8) = vv;
    }
  } else {
    // ---- q/k rows: packed 8B stores (4 consecutive kd per thread) ----
    const float* bias = (m0 < 256) ? q_b : k_b;
    bf16* dst = (m0 < 256) ? qT : kT;
    int mb = (m0 < 256) ? m0 : m0 - 256;
#pragma unroll
    for (int r = 0; r < 4; ++r)
#pragma unroll
      for (int f = 0; f < 4; ++f) {
        int n = n0b + wn * 64 + f * 16 + li;
        int rowg = mb + wm * 64 + r * 16 + qd * 4;
        int h = rowg >> 5, kd = rowg & 31;
        union { bf16 e[4]; uint2 u; } pk;
#pragma unroll
        for (int rr = 0; rr < 4; ++rr)
          pk.e[rr] = __float2bfloat16(acc[r][f][rr] + sf(bias[rowg + rr]));
        *(uint2*)(dst + (((size_t)b * NH + h) * NTOK + n) * KD + kd) = pk.u;
      }
  }
}

// ---------------- K2: scores, SWAPPED-operand QK^T (m in regs, n in lanes) ----------------
__global__ __launch_bounds__(1024, 4) void k_scores(const bf16* __restrict__ qT,
    const bf16* __restrict__ kT, const float* __restrict__ bias_full,
    const float* __restrict__ th1_w,
    const float* __restrict__ th2_w, const float* __restrict__ th2_b,
    bf16* __restrict__ P, int nb) {
  __shared__ float s_th1[64], s_th2[64], s_t2b[8];
  __shared__ float s_part[16][8][16];    // 8 KB
  __shared__ float s_invl[8][16];
  int t = threadIdx.x;
  // fold SCALE*log2e into TH1 weights (bias premix already *log2e)
  if (t < 64) { s_th1[t] = sf(th1_w[t]) * (SCALE * LOG2E); s_th2[t] = sf(th2_w[t]); }
  if (t >= 64 && t < 72) s_t2b[t - 64] = sf(th2_b[t - 64]);
  int id = blockIdx.x;
  int b, nt;
  if ((nb & 7) == 0) {
    int per = nb >> 3;
    int xcd = id & 7, slot = id >> 3;
    b = xcd * per + (slot % per);
    nt = slot / per;            // [0,16)
  } else { b = id >> 4; nt = id & 15; }
  int n0 = nt * 16;
  int wave = t >> 6, lane = t & 63, qd = lane >> 4, li = lane & 15;
  int ms = wave * 16;           // this wave's 16-m slice

  // ---- QK^T swapped: S[h][r] at (m = ms+qd*4+r, n = n0+li) ----
  f32x4 S[8];
#pragma unroll
  for (int h = 0; h < 8; ++h) {
    bf16v8 Ak = *(const bf16v8*)(kT + (((size_t)b * NH + h) * NTOK + ms + li) * KD + qd * 8);
    bf16v8 Bq = *(const bf16v8*)(qT + (((size_t)b * NH + h) * NTOK + n0 + li) * KD + qd * 8);
    f32x4 c = {0.f, 0.f, 0.f, 0.f};
    S[h] = __builtin_amdgcn_mfma_f32_16x16x32_bf16(Ak, Bq, c, 0, 0, 0);
  }
  __syncthreads();   // th weights staged in LDS

  // ---- TH1 (SGPR weights) + premixed bias + exp2 ----
  f32x4 E[8];
  {
    float w1[64];
#pragma unroll
    for (int i = 0; i < 64; ++i) w1[i] = rfl(s_th1[i]);
#pragma unroll
    for (int r = 0; r < 4; ++r) {
#pragma unroll
      for (int g = 0; g < 8; ++g) {
        float a = bias_full[((size_t)g * 256 + ms + qd * 4 + r) * 256 + n0 + li];
#pragma unroll
        for (int h = 0; h < 8; ++h) a += w1[g * 8 + h] * S[h][r];
        E[g][r] = exp2f(fminf(a, 43.3f));
      }
    }
  }
  // ---- row sums: 3 in-thread adds + 2 shfl per g ----
#pragma unroll
  for (int g = 0; g < 8; ++g) {
    float v = (E[g][0] + E[g][1]) + (E[g][2] + E[g][3]);
    v += __shfl_xor(v, 16, 64);
    v += __shfl_xor(v, 32, 64);
    if (qd == 0) s_part[wave][g][li] = v;
  }
  __syncthreads();
  if (t < 128) {
    int g = t >> 4, n = t & 15;
    float ssum = 0.f;
#pragma unroll
    for (int w2 = 0; w2 < 16; ++w2) ssum += s_part[w2][g][n];
    s_invl[g][n] = 1.0f / ssum;
  }
  __syncthreads();
#pragma unroll
  for (int g = 0; g < 8; ++g) {
    float inv = s_invl[g][li];
#pragma unroll
    for (int r = 0; r < 4; ++r) E[g][r] *= inv;
  }

  // ---- TH2 (SGPR weights) + direct packed 8B P store (blocked layout unchanged) ----
  {
    float w2[64], b2[8];
#pragma unroll
    for (int i = 0; i < 64; ++i) w2[i] = rfl(s_th2[i]);
#pragma unroll
    for (int i = 0; i < 8; ++i) b2[i] = rfl(s_t2b[i]);
    size_t pbase = (size_t)b * NH * 65536 + (size_t)nt * 4096 +
                   (size_t)(wave >> 1) * 512 + li * 32 + (wave & 1) * 16 + qd * 4;
#pragma unroll
    for (int g2 = 0; g2 < 8; ++g2) {
      union { bf16 e[4]; uint2 u; } pk;
#pragma unroll
      for (int r = 0; r < 4; ++r) {
        float a = b2[g2];
#pragma unroll
        for (int g = 0; g < 8; ++g) a += w2[g2 * 8 + g] * E[g][r];
        pk.e[r] = __float2bfloat16(a);
      }
      *(uint2*)(P + pbase + (size_t)g2 * 65536) = pk.u;
    }
  }
}

// ---------------- K3: O = P@V + dwconv + relu -> act[b,n,ch] ----------------
// R6: LDS 140KB -> ~74KB (act_s replaced by per-wave 640B transpose buf) -> 2 blocks/CU;
// dwconv window via aligned ds_read_b64 + qd-boundary shuffles (halo == spatial zero-pad).
static __device__ __forceinline__ int vswz(int ch, int tok) {
  return tok ^ ((ch & 7) << 3);
}

__global__ __launch_bounds__(512, 4) void k_pv(const bf16* __restrict__ P,
    const bf16* __restrict__ v4,
    const float* __restrict__ vl_w, const float* __restrict__ vl_b,
    bf16* __restrict__ act, int nb) {
  __shared__ bf16 v_s[128][256];     // 64 KB, bank-swizzled via vswz()
  __shared__ float wv_s[1152];       // dw weights for this head: 4.5 KB
  __shared__ float vb_s[128];
  __shared__ bf16 tbuf[8][16][20];   // per-wave 16n x 16ch transpose tile (5 KB)
  int id = blockIdx.x;
  int b, h;
  if ((nb & 7) == 0) {
    int per = nb >> 3;
    int xcd = id & 7, slot = id >> 3;
    b = xcd * per + (slot % per);
    h = slot / per;            // [0,8)
  } else { b = id >> 3; h = id & 7; }
  int t = threadIdx.x;
  int wave = t >> 6, lane = t & 63;
  int qd = lane >> 4, li = lane & 15;
  int nw = wave * 32;                // 32 tokens per wave
  int nwt = wave * 2;                // n-tile base
  const bf16* Pb = P + ((size_t)b * NH + h) * 65536;
  const bf16* Vb = v4 + ((size_t)b * DH + h * DHEAD) * NTOK;

  // --- prefetch ALL P fragments (latency hides under V staging; drained by barrier) ---
  bf16v8 Af[4][2][2];
#pragma unroll
  for (int mi = 0; mi < 4; ++mi)
#pragma unroll
    for (int s = 0; s < 2; ++s)
#pragma unroll
      for (int r = 0; r < 2; ++r)
        Af[mi][s][r] = *(const bf16v8*)(Pb + (size_t)(nwt + r) * 4096 +
                                        (mi * 2 + s) * 512 + li * 32 + qd * 8);

  // --- stage V slab (coalesced 16B, swizzled LDS dest) + dw weights ---
#pragma unroll
  for (int p = 0; p < 8; ++p) {
    int idx = p * 512 + t;             // 16-B granule id, 4096 total
    int ch = idx >> 5, tok = (idx & 31) * 8;
    *(bf16v8*)&v_s[ch][vswz(ch, tok)] = *(const bf16v8*)(Vb + (size_t)ch * NTOK + tok);
  }
  for (int i = t; i < 1152; i += 512) wv_s[i] = sf(vl_w[(size_t)h * DHEAD * 9 + i]);
  if (t < 128) vb_s[t] = sf(vl_b[h * DHEAD + t]);
  __syncthreads();

  // --- PV GEMM: B operand from swizzled LDS ---
  f32x4 acc[2][8];
#pragma unroll
  for (int r = 0; r < 2; ++r)
#pragma unroll
    for (int f = 0; f < 8; ++f) acc[r][f] = (f32x4){0.f, 0.f, 0.f, 0.f};
#pragma unroll
  for (int mi = 0; mi < 4; ++mi) {
    int m0 = mi * 64;
#pragma unroll
    for (int s = 0; s < 2; ++s) {
      bf16v8 Bf[8];
#pragma unroll
      for (int f = 0; f < 8; ++f) {
        int ch = f * 16 + li;
        Bf[f] = *(const bf16v8*)&v_s[ch][vswz(ch, m0 + s * 32 + qd * 8)];
      }
#pragma unroll
      for (int f = 0; f < 8; ++f)
#pragma unroll
        for (int r = 0; r < 2; ++r)
          acc[r][f] = __builtin_amdgcn_mfma_f32_16x16x32_bf16(Af[mi][s][r], Bf[f], acc[r][f], 0, 0, 0);
    }
  }

  // --- epilogue: dwconv via b64+shfl; per-(f,r) transpose through tbuf; 8B stores ---
#pragma unroll
  for (int f = 0; f < 8; ++f) {
    int chl = f * 16 + li;
    float wv[9];
#pragma unroll
    for (int j = 0; j < 9; ++j) wv[j] = wv_s[chl * 9 + j];
    float vb = vb_s[chl];
#pragma unroll
    for (int r = 0; r < 2; ++r) {
      int y = (nw + r * 16) >> 4;
      float vvv[3][6];
#pragma unroll
      for (int yy = 0; yy < 3; ++yy) {
        int y3 = y - 1 + yy;
        float e0 = 0.f, e1 = 0.f, e2 = 0.f, e3 = 0.f;
        if (y3 >= 0 && y3 < 16) {
          int tok = y3 * 16 + qd * 4;          // 8B-aligned, within one 16B granule
          union { uint2 u; bf16 e[4]; } w4;
          w4.u = *(const uint2*)&v_s[chl][vswz(chl, tok)];
          e0 = __bfloat162float(w4.e[0]);
          e1 = __bfloat162float(w4.e[1]);
          e2 = __bfloat162float(w4.e[2]);
          e3 = __bfloat162float(w4.e[3]);
        }
        float lft = __shfl_up(e3, 16, 64);     // lane-16 = qd-1, same li
        float rgt = __shfl_down(e0, 16, 64);   // lane+16 = qd+1, same li
        if (qd == 0) lft = 0.f;                // x = -1 -> spatial pad
        if (qd == 3) rgt = 0.f;                // x = 16 -> spatial pad
        vvv[yy][0] = lft; vvv[yy][1] = e0; vvv[yy][2] = e1;
        vvv[yy][3] = e2;  vvv[yy][4] = e3; vvv[yy][5] = rgt;
      }
#pragma unroll
      for (int rr = 0; rr < 4; ++rr) {
        float s = vb;
#pragma unroll
        for (int yy = 0; yy < 3; ++yy)
#pragma unroll
          for (int j = 0; j < 3; ++j)
            s += vvv[yy][rr + j] * wv[yy * 3 + j];
        float v = fmaxf(acc[r][f][rr] + s, 0.f);
        tbuf[wave][qd * 4 + rr][li] = __float2bfloat16(v);   // conflict-free rows
      }
      // wave-private read-back: thread (qd,li) -> n = nw+r*16+li, ch = f*16+qd*4..+3
      uint2 pr = *(const uint2*)&tbuf[wave][li][qd * 4];      // 8B-aligned (row=40B)
      *(uint2*)(act + ((size_t)b * NTOK + nw + r * 16 + li) * DH +
                h * DHEAD + f * 16 + qd * 4) = pr;
    }
  }
}

// ---------------- K4: proj GEMM out[b,dim,tok] = wp @ act^T + proj_b ----------------
__global__ __launch_bounds__(256, 4) void k_proj(const bf16* __restrict__ act,
    const bf16* __restrict__ proj_w, const float* __restrict__ proj_b,
    int b_base, int nb, float* __restrict__ out) {
  int id = blockIdx.x;
  int b, mt;
  if ((nb & 7) == 0) {
    int per = nb >> 3;
    int xcd = id & 7, slot = id >> 3;
    b = xcd * per + (slot % per);
    mt = slot / per;            // [0,6)
  } else { b = id / 6; mt = id % 6; }
  int m0 = mt * 64;
  int bg = b_base + b;
  int wave = threadIdx.x >> 6, lane = threadIdx.x & 63;
  int qd = lane >> 4, li = lane & 15;
  int n0 = wave * 64;
  f32x4 acc[4][4];
#pragma unroll
  for (int r = 0; r < 4; ++r)
#pragma unroll
    for (int f = 0; f < 4; ++f) acc[r][f] = (f32x4){0.f, 0.f, 0.f, 0.f};
  for (int k0 = 0; k0 < DH; k0 += 32) {
    bf16v8 Af[4], Bf[4];
#pragma unroll
    for (int r = 0; r < 4; ++r)
      Af[r] = *(const bf16v8*)(proj_w + (size_t)(m0 + r * 16 + li) * DH + k0 + qd * 8);
#pragma unroll
    for (int f = 0; f < 4; ++f)
      Bf[f] = *(const bf16v8*)(act + ((size_t)b * NTOK + n0 + f * 16 + li) * DH + k0 + qd * 8);
#pragma unroll
    for (int r = 0; r < 4; ++r)
#pragma unroll
      for (int f = 0; f < 4; ++f)
        acc[r][f] = __builtin_amdgcn_mfma_f32_16x16x32_bf16(Af[r], Bf[f], acc[r][f], 0, 0, 0);
  }
#pragma unroll
  for (int r = 0; r < 4; ++r)
#pragma unroll
    for (int f = 0; f < 4; ++f) {
      int n = n0 + f * 16 + li;
#pragma unroll
      for (int rr = 0; rr < 4; ++rr) {
        int dim = m0 + r * 16 + qd * 4 + rr;
        out[((size_t)bg * DIM + dim) * NTOK + n] = acc[r][f][rr] + sf(proj_b[dim]);
      }
    }
}

extern "C" void kernel_launch(void* const* d_in, const int* in_sizes, int n_in,
                              void* d_out, int out_size, void* d_ws, size_t ws_size,
                              hipStream_t stream) {
  const float* x      = (const float*)d_in[0];
  const float* q_w    = (const float*)d_in[1];
  const float* q_b    = (const float*)d_in[2];
  const float* k_w    = (const float*)d_in[3];
  const float* k_b    = (const float*)d_in[4];
  const float* v_w    = (const float*)d_in[5];
  const float* v_b    = (const float*)d_in[6];
  const float* vl_w   = (const float*)d_in[7];
  const float* vl_b   = (const float*)d_in[8];
  const float* th1_w  = (const float*)d_in[9];
  const float* th1_b  = (const float*)d_in[10];
  const float* th2_w  = (const float*)d_in[11];
  const float* th2_b  = (const float*)d_in[12];
  const float* proj_w = (const float*)d_in[13];
  const float* proj_b = (const float*)d_in[14];
  const float* attn_b = (const float*)d_in[15];
  const int*   idxs   = (const int*)d_in[16];
  int n_off = in_sizes[15] / NH;
  float* out = (float*)d_out;

  const size_t WQ = 98304, WK = 98304, WV = 393216, WP = 393216;
  const size_t WTOT = WQ + WK + WV + WP;                       // 983040 elem
  const size_t BFULL = (size_t)NH * NTOK * NTOK;               // 524288 f32
  const size_t PB_XT = (size_t)NTOK * DIM;                     // 98304
  const size_t PB_QK = (size_t)NH * NTOK * KD;                 // 65536
  const size_t PB_V  = (size_t)DH * NTOK;                      // 262144
  const size_t PB_AC = (size_t)NTOK * DH;                      // 262144
  const size_t PB_P  = (size_t)NH * NTOK * NTOK;               // 524288
  const size_t perb  = (PB_XT + 2 * PB_QK + PB_V + PB_AC + PB_P) * 2;  // 2555904 B
  const size_t fixed = WTOT * 2 + BFULL * 4;

  char* w = (char*)d_ws;
  bf16* wcvt = (bf16*)w;  w += WTOT * 2;
  bf16* wq = wcvt;
  bf16* wk = wcvt + WQ;
  bf16* wv = wcvt + WQ + WK;
  bf16* wp = wcvt + WQ + WK + WV;
  float* bias_full = (float*)w;  w += BFULL * 4;

  size_t rem = (ws_size > fixed) ? (ws_size - fixed) : 0;
  int CH = (int)(rem / perb);
  if (CH > BB) CH = BB;
  if (CH >= 8) CH &= ~7;      // multiple of 8 -> XCD swizzle active
  if (CH < 1) CH = 1;

  bf16* xT  = (bf16*)w;  w += (size_t)CH * PB_XT * 2;
  bf16* qT  = (bf16*)w;  w += (size_t)CH * PB_QK * 2;
  bf16* kT  = (bf16*)w;  w += (size_t)CH * PB_QK * 2;
  bf16* v4  = (bf16*)w;  w += (size_t)CH * PB_V * 2;
  bf16* act = (bf16*)w;  w += (size_t)CH * PB_AC * 2;
  bf16* P   = (bf16*)w;  w += (size_t)CH * PB_P * 2;

  k_convert<<<(int)(WTOT / 256), 256, 0, stream>>>(q_w, k_w, v_w, proj_w, wcvt);
  k_bias<<<256, 256, 0, stream>>>(attn_b, idxs, n_off, th1_w, th1_b, bias_full);

  for (int c0 = 0; c0 < BB; c0 += CH) {
    int cb = (BB - c0 < CH) ? (BB - c0) : CH;
    k_transpose_x<<<dim3(12, 8, cb), 256, 0, stream>>>(x + (size_t)c0 * DIM * NTOK, xT);
    k_qkv<<<cb * 24, 256, 0, stream>>>(xT, wcvt, q_b, k_b, v_b, qT, kT, v4, cb);
    k_scores<<<cb * 16, 1024, 0, stream>>>(qT, kT, bias_full,
                                           th1_w, th2_w, th2_b, P, cb);
    k_pv<<<cb * 16 / 2, 512, 0, stream>>>(P, v4, vl_w, vl_b, act, cb);
    k_proj<<<cb * 6, 256, 0, stream>>>(act, wp, proj_b, c0, cb, out);
  }
}

// Round 7
// 407.474 us; speedup vs baseline: 1.3760x; 1.2036x over previous
//
#include <hip/hip_runtime.h>
#include <hip/hip_bf16.h>

typedef __hip_bfloat16 bf16;
typedef __bf16 bf16v8 __attribute__((ext_vector_type(8)));
typedef float f32x4 __attribute__((ext_vector_type(4)));

#define BB    128
#define DIM   384
#define NTOK  256
#define NH    8
#define KD    32
#define DHEAD 128
#define DH    1024
#define SCALE 0.17677669529663687f
#define LOG2E 1.4426950408889634f

// sanitize boundary reads: NaN->0, clamp huge
static __device__ __forceinline__ float sf(float x) {
  return (x == x) ? fminf(fmaxf(x, -1e4f), 1e4f) : 0.f;
}

static __device__ __forceinline__ float rfl(float x) {
  return __int_as_float(__builtin_amdgcn_readfirstlane(__float_as_int(x)));
}

#define GLOAD_LDS16(gsrc, ldst)                                                \
  __builtin_amdgcn_global_load_lds(                                            \
      (const __attribute__((address_space(1))) void*)(gsrc),                   \
      (__attribute__((address_space(3))) void*)(ldst), 16, 0, 0)

// ---------------- K-1a: fp32 weights -> bf16 copies in ws ----------------
__global__ __launch_bounds__(256) void k_convert(const float* __restrict__ qw,
    const float* __restrict__ kw, const float* __restrict__ vw,
    const float* __restrict__ pw, bf16* __restrict__ dst) {
  int i = blockIdx.x * 256 + threadIdx.x;
  float v;
  if (i < 98304)       v = qw[i];
  else if (i < 196608) v = kw[i - 98304];
  else if (i < 589824) v = vw[i - 196608];
  else                 v = pw[i - 589824];
  dst[i] = __float2bfloat16(sf(v));
}

// ---------------- K-1b: bias premix, TRANSPOSED layout [g][m][n], log2e-folded ----------------
__global__ __launch_bounds__(256) void k_bias(const float* __restrict__ ab,
    const int* __restrict__ idxs, int n_off,
    const float* __restrict__ th1_w, const float* __restrict__ th1_b,
    float* __restrict__ bias_full) {
  int mn = blockIdx.x * 256 + threadIdx.x;   // m-major for coalesced writes
  int m = mn >> 8, n = mn & 255;
  int idx = idxs[n * 256 + m];
  float bh[8];
#pragma unroll
  for (int h = 0; h < 8; ++h) bh[h] = sf(ab[h * n_off + idx]);
#pragma unroll
  for (int g = 0; g < 8; ++g) {
    float a = sf(th1_b[g]);
#pragma unroll
    for (int h = 0; h < 8; ++h) a += sf(th1_w[g * 8 + h]) * bh[h];
    bias_full[((size_t)g * 256 + m) * 256 + n] = a * LOG2E;
  }
}

// ---------------- K0: x fp32 [cb,384,256] -> xT bf16 [cb,256,384] ----------------
__global__ __launch_bounds__(256) void k_transpose_x(const float* __restrict__ x,
                                                     bf16* __restrict__ xT) {
  __shared__ bf16 tile[32][33];
  int b = blockIdx.z;
  int c0 = blockIdx.x * 32;
  int n0 = blockIdx.y * 32;
  int t = threadIdx.x;
  int tn = t & 31, tc = t >> 5;
#pragma unroll
  for (int p = 0; p < 4; ++p)
    tile[tc + p * 8][tn] =
        __float2bfloat16(sf(x[((size_t)b * DIM + c0 + tc + p * 8) * NTOK + n0 + tn]));
  __syncthreads();
  int wc = t & 31, wn = t >> 5;
#pragma unroll
  for (int p = 0; p < 4; ++p)
    xT[((size_t)b * NTOK + n0 + wn + p * 8) * DIM + c0 + wc] = tile[wc][wn + p * 8];
}

// ---------------- K1: QKV GEMM, LDS-staged m97-style ----------------
__global__ __launch_bounds__(256, 3) void k_qkv(const bf16* __restrict__ xT,
    const bf16* __restrict__ W, const float* __restrict__ q_b,
    const float* __restrict__ k_b, const float* __restrict__ v_b,
    bf16* __restrict__ qT, bf16* __restrict__ kT, bf16* __restrict__ v4,
    int nb) {
  __shared__ __align__(16) char smem[34816];   // stage A16K+B16K | v-epilogue tile 128x136 bf16
  bf16* sA = (bf16*)smem;                      // [128][64]
  bf16* sB = (bf16*)(smem + 16384);            // [128][64]
  bf16* actt = (bf16*)smem;                    // [128][136]

  int id = blockIdx.x;
  int b, tile;
  if ((nb & 7) == 0) {
    int per = nb >> 3;
    int xcd = id & 7, slot = id >> 3;
    b = xcd * per + (slot % per);
    tile = slot / per;          // [0,24)
  } else { b = id / 24; tile = id % 24; }
  int mt = tile >> 1, nt = tile & 1;
  int m0 = mt * 128, n0b = nt * 128;
  int t = threadIdx.x;
  int wave = t >> 6, lane = t & 63;
  int wm = wave >> 1, wn = wave & 1;
  int qd = lane >> 4, li = lane & 15;
  const bf16* xTb = xT + ((size_t)b * NTOK + n0b) * DIM;

  f32x4 acc[4][4];
#pragma unroll
  for (int r = 0; r < 4; ++r)
#pragma unroll
    for (int f = 0; f < 4; ++f) acc[r][f] = (f32x4){0.f, 0.f, 0.f, 0.f};

  for (int ks = 0; ks < 6; ++ks) {
    int k0 = ks * 64;
    __syncthreads();            // prev compute done -> safe to overwrite LDS
#pragma unroll
    for (int i = 0; i < 8; ++i) {
      int g = wave * 512 + i * 64 + lane;      // [0,2048) granules; <1024 -> A
      int gg = g & 1023;
      int row = gg >> 3, slot = gg & 7;
      int col = ((slot ^ (row & 7)) << 3) + k0;
      const bf16* src = (g < 1024)
          ? (W + (size_t)(m0 + row) * DIM + col)
          : (xTb + (size_t)row * DIM + col);
      GLOAD_LDS16(src, smem + (size_t)(wave * 512 + i * 64) * 16);
    }
    __syncthreads();            // staging drained (vmcnt(0) at barrier)
#pragma unroll
    for (int s = 0; s < 2; ++s) {
      bf16v8 Afr[4], Bfr[4];
#pragma unroll
      for (int r = 0; r < 4; ++r) {
        int row = wm * 64 + r * 16 + li;
        Afr[r] = *(const bf16v8*)(sA + row * 64 + (((s * 4 + qd) ^ (row & 7)) << 3));
      }
#pragma unroll
      for (int f = 0; f < 4; ++f) {
        int row = wn * 64 + f * 16 + li;
        Bfr[f] = *(const bf16v8*)(sB + row * 64 + (((s * 4 + qd) ^ (row & 7)) << 3));
      }
#pragma unroll
      for (int r = 0; r < 4; ++r)
#pragma unroll
        for (int f = 0; f < 4; ++f)
          acc[r][f] = __builtin_amdgcn_mfma_f32_16x16x32_bf16(Afr[r], Bfr[f], acc[r][f], 0, 0, 0);
    }
  }
  __syncthreads();              // all LDS reads done before smem reuse

  if (m0 >= 512) {
    // ---- v rows: restage through LDS -> coalesced 16B stores to v4[ch][tok] ----
    int ch0 = m0 - 512;
#pragma unroll
    for (int r = 0; r < 4; ++r)
#pragma unroll
      for (int f = 0; f < 4; ++f) {
        int coll = wn * 64 + f * 16 + li;
#pragma unroll
        for (int rr = 0; rr < 4; ++rr) {
          int rowl = wm * 64 + r * 16 + qd * 4 + rr;
          actt[rowl * 136 + coll] =
              __float2bfloat16(acc[r][f][rr] + sf(v_b[ch0 + rowl]));
        }
      }
    __syncthreads();
#pragma unroll
    for (int it = 0; it < 8; ++it) {
      int g = it * 256 + t;
      int row = g >> 4, c16 = g & 15;
      bf16v8 vv = *(const bf16v8*)(actt + row * 136 + c16 * 8);
      *(bf16v8*)(v4 + ((size_t)b * DH + ch0 + row) * NTOK + n0b + c16 * 8) = vv;
    }
  } else {
    // ---- q/k rows: packed 8B stores (4 consecutive kd per thread) ----
    const float* bias = (m0 < 256) ? q_b : k_b;
    bf16* dst = (m0 < 256) ? qT : kT;
    int mb = (m0 < 256) ? m0 : m0 - 256;
#pragma unroll
    for (int r = 0; r < 4; ++r)
#pragma unroll
      for (int f = 0; f < 4; ++f) {
        int n = n0b + wn * 64 + f * 16 + li;
        int rowg = mb + wm * 64 + r * 16 + qd * 4;
        int h = rowg >> 5, kd = rowg & 31;
        union { bf16 e[4]; uint2 u; } pk;
#pragma unroll
        for (int rr = 0; rr < 4; ++rr)
          pk.e[rr] = __float2bfloat16(acc[r][f][rr] + sf(bias[rowg + rr]));
        *(uint2*)(dst + (((size_t)b * NH + h) * NTOK + n) * KD + kd) = pk.u;
      }
  }
}

// ---------------- K2: scores, SWAPPED-operand QK^T (m in regs, n in lanes) ----------------
__global__ __launch_bounds__(1024, 4) void k_scores(const bf16* __restrict__ qT,
    const bf16* __restrict__ kT, const float* __restrict__ bias_full,
    const float* __restrict__ th1_w,
    const float* __restrict__ th2_w, const float* __restrict__ th2_b,
    bf16* __restrict__ P, int nb) {
  __shared__ float s_th1[64], s_th2[64], s_t2b[8];
  __shared__ float s_part[16][8][16];    // 8 KB
  __shared__ float s_invl[8][16];
  int t = threadIdx.x;
  // fold SCALE*log2e into TH1 weights (bias premix already *log2e)
  if (t < 64) { s_th1[t] = sf(th1_w[t]) * (SCALE * LOG2E); s_th2[t] = sf(th2_w[t]); }
  if (t >= 64 && t < 72) s_t2b[t - 64] = sf(th2_b[t - 64]);
  int id = blockIdx.x;
  int b, nt;
  if ((nb & 7) == 0) {
    int per = nb >> 3;
    int xcd = id & 7, slot = id >> 3;
    b = xcd * per + (slot % per);
    nt = slot / per;            // [0,16)
  } else { b = id >> 4; nt = id & 15; }
  int n0 = nt * 16;
  int wave = t >> 6, lane = t & 63, qd = lane >> 4, li = lane & 15;
  int ms = wave * 16;           // this wave's 16-m slice

  // ---- QK^T swapped: S[h][r] at (m = ms+qd*4+r, n = n0+li) ----
  f32x4 S[8];
#pragma unroll
  for (int h = 0; h < 8; ++h) {
    bf16v8 Ak = *(const bf16v8*)(kT + (((size_t)b * NH + h) * NTOK + ms + li) * KD + qd * 8);
    bf16v8 Bq = *(const bf16v8*)(qT + (((size_t)b * NH + h) * NTOK + n0 + li) * KD + qd * 8);
    f32x4 c = {0.f, 0.f, 0.f, 0.f};
    S[h] = __builtin_amdgcn_mfma_f32_16x16x32_bf16(Ak, Bq, c, 0, 0, 0);
  }
  __syncthreads();   // th weights staged in LDS

  // ---- TH1 (SGPR weights) + premixed bias + exp2 ----
  f32x4 E[8];
  {
    float w1[64];
#pragma unroll
    for (int i = 0; i < 64; ++i) w1[i] = rfl(s_th1[i]);
#pragma unroll
    for (int r = 0; r < 4; ++r) {
#pragma unroll
      for (int g = 0; g < 8; ++g) {
        float a = bias_full[((size_t)g * 256 + ms + qd * 4 + r) * 256 + n0 + li];
#pragma unroll
        for (int h = 0; h < 8; ++h) a += w1[g * 8 + h] * S[h][r];
        E[g][r] = exp2f(fminf(a, 43.3f));
      }
    }
  }
  // ---- row sums: 3 in-thread adds + 2 shfl per g ----
#pragma unroll
  for (int g = 0; g < 8; ++g) {
    float v = (E[g][0] + E[g][1]) + (E[g][2] + E[g][3]);
    v += __shfl_xor(v, 16, 64);
    v += __shfl_xor(v, 32, 64);
    if (qd == 0) s_part[wave][g][li] = v;
  }
  __syncthreads();
  if (t < 128) {
    int g = t >> 4, n = t & 15;
    float ssum = 0.f;
#pragma unroll
    for (int w2 = 0; w2 < 16; ++w2) ssum += s_part[w2][g][n];
    s_invl[g][n] = 1.0f / ssum;
  }
  __syncthreads();
#pragma unroll
  for (int g = 0; g < 8; ++g) {
    float inv = s_invl[g][li];
#pragma unroll
    for (int r = 0; r < 4; ++r) E[g][r] *= inv;
  }

  // ---- TH2 (SGPR weights) + direct packed 8B P store (blocked layout unchanged) ----
  {
    float w2[64], b2[8];
#pragma unroll
    for (int i = 0; i < 64; ++i) w2[i] = rfl(s_th2[i]);
#pragma unroll
    for (int i = 0; i < 8; ++i) b2[i] = rfl(s_t2b[i]);
    size_t pbase = (size_t)b * NH * 65536 + (size_t)nt * 4096 +
                   (size_t)(wave >> 1) * 512 + li * 32 + (wave & 1) * 16 + qd * 4;
#pragma unroll
    for (int g2 = 0; g2 < 8; ++g2) {
      union { bf16 e[4]; uint2 u; } pk;
#pragma unroll
      for (int r = 0; r < 4; ++r) {
        float a = b2[g2];
#pragma unroll
        for (int g = 0; g < 8; ++g) a += w2[g2 * 8 + g] * E[g][r];
        pk.e[r] = __float2bfloat16(a);
      }
      *(uint2*)(P + pbase + (size_t)g2 * 65536) = pk.u;
    }
  }
}

// ---------------- K3: O = P@V + dwconv + relu -> act[b,n,ch] ----------------
static __device__ __forceinline__ int vswz(int ch, int tok) {
  return tok ^ ((ch & 7) << 3);
}

__global__ __launch_bounds__(512, 4) void k_pv(const bf16* __restrict__ P,
    const bf16* __restrict__ v4,
    const float* __restrict__ vl_w, const float* __restrict__ vl_b,
    bf16* __restrict__ act, int nb) {
  __shared__ bf16 v_s[128][256];     // 64 KB, bank-swizzled via vswz()
  __shared__ float wv_s[1152];       // dw weights for this head: 4.5 KB
  __shared__ float vb_s[128];
  __shared__ bf16 tbuf[8][16][20];   // per-wave 16n x 16ch transpose tile (5 KB)
  int id = blockIdx.x;
  int b, h;
  if ((nb & 7) == 0) {
    int per = nb >> 3;
    int xcd = id & 7, slot = id >> 3;
    b = xcd * per + (slot % per);
    h = slot / per;            // [0,8)
  } else { b = id >> 3; h = id & 7; }
  int t = threadIdx.x;
  int wave = t >> 6, lane = t & 63;
  int qd = lane >> 4, li = lane & 15;
  int nw = wave * 32;                // 32 tokens per wave
  int nwt = wave * 2;                // n-tile base
  const bf16* Pb = P + ((size_t)b * NH + h) * 65536;
  const bf16* Vb = v4 + ((size_t)b * DH + h * DHEAD) * NTOK;

  // --- prefetch ALL P fragments (latency hides under V staging; drained by barrier) ---
  bf16v8 Af[4][2][2];
#pragma unroll
  for (int mi = 0; mi < 4; ++mi)
#pragma unroll
    for (int s = 0; s < 2; ++s)
#pragma unroll
      for (int r = 0; r < 2; ++r)
        Af[mi][s][r] = *(const bf16v8*)(Pb + (size_t)(nwt + r) * 4096 +
                                        (mi * 2 + s) * 512 + li * 32 + qd * 8);

  // --- stage V slab (coalesced 16B, swizzled LDS dest) + dw weights ---
#pragma unroll
  for (int p = 0; p < 8; ++p) {
    int idx = p * 512 + t;             // 16-B granule id, 4096 total
    int ch = idx >> 5, tok = (idx & 31) * 8;
    *(bf16v8*)&v_s[ch][vswz(ch, tok)] = *(const bf16v8*)(Vb + (size_t)ch * NTOK + tok);
  }
  for (int i = t; i < 1152; i += 512) wv_s[i] = sf(vl_w[(size_t)h * DHEAD * 9 + i]);
  if (t < 128) vb_s[t] = sf(vl_b[h * DHEAD + t]);
  __syncthreads();

  // --- PV GEMM: B operand from swizzled LDS ---
  f32x4 acc[2][8];
#pragma unroll
  for (int r = 0; r < 2; ++r)
#pragma unroll
    for (int f = 0; f < 8; ++f) acc[r][f] = (f32x4){0.f, 0.f, 0.f, 0.f};
#pragma unroll
  for (int mi = 0; mi < 4; ++mi) {
    int m0 = mi * 64;
#pragma unroll
    for (int s = 0; s < 2; ++s) {
      bf16v8 Bf[8];
#pragma unroll
      for (int f = 0; f < 8; ++f) {
        int ch = f * 16 + li;
        Bf[f] = *(const bf16v8*)&v_s[ch][vswz(ch, m0 + s * 32 + qd * 8)];
      }
#pragma unroll
      for (int f = 0; f < 8; ++f)
#pragma unroll
        for (int r = 0; r < 2; ++r)
          acc[r][f] = __builtin_amdgcn_mfma_f32_16x16x32_bf16(Af[mi][s][r], Bf[f], acc[r][f], 0, 0, 0);
    }
  }

  // --- epilogue: dwconv via b64+shfl; per-(f,r) transpose through tbuf; 8B stores ---
#pragma unroll
  for (int f = 0; f < 8; ++f) {
    int chl = f * 16 + li;
    float wv[9];
#pragma unroll
    for (int j = 0; j < 9; ++j) wv[j] = wv_s[chl * 9 + j];
    float vb = vb_s[chl];
#pragma unroll
    for (int r = 0; r < 2; ++r) {
      int y = (nw + r * 16) >> 4;
      float vvv[3][6];
#pragma unroll
      for (int yy = 0; yy < 3; ++yy) {
        int y3 = y - 1 + yy;
        float e0 = 0.f, e1 = 0.f, e2 = 0.f, e3 = 0.f;
        if (y3 >= 0 && y3 < 16) {
          int tok = y3 * 16 + qd * 4;          // 8B-aligned, within one 16B granule
          union { uint2 u; bf16 e[4]; } w4;
          w4.u = *(const uint2*)&v_s[chl][vswz(chl, tok)];
          e0 = __bfloat162float(w4.e[0]);
          e1 = __bfloat162float(w4.e[1]);
          e2 = __bfloat162float(w4.e[2]);
          e3 = __bfloat162float(w4.e[3]);
        }
        float lft = __shfl_up(e3, 16, 64);     // lane-16 = qd-1, same li
        float rgt = __shfl_down(e0, 16, 64);   // lane+16 = qd+1, same li
        if (qd == 0) lft = 0.f;                // x = -1 -> spatial pad
        if (qd == 3) rgt = 0.f;                // x = 16 -> spatial pad
        vvv[yy][0] = lft; vvv[yy][1] = e0; vvv[yy][2] = e1;
        vvv[yy][3] = e2;  vvv[yy][4] = e3; vvv[yy][5] = rgt;
      }
#pragma unroll
      for (int rr = 0; rr < 4; ++rr) {
        float s = vb;
#pragma unroll
        for (int yy = 0; yy < 3; ++yy)
#pragma unroll
          for (int j = 0; j < 3; ++j)
            s += vvv[yy][rr + j] * wv[yy * 3 + j];
        float v = fmaxf(acc[r][f][rr] + s, 0.f);
        tbuf[wave][qd * 4 + rr][li] = __float2bfloat16(v);   // conflict-free rows
      }
      // wave-private read-back: thread (qd,li) -> n = nw+r*16+li, ch = f*16+qd*4..+3
      uint2 pr = *(const uint2*)&tbuf[wave][li][qd * 4];      // 8B-aligned (row=40B)
      *(uint2*)(act + ((size_t)b * NTOK + nw + r * 16 + li) * DH +
                h * DHEAD + f * 16 + qd * 4) = pr;
    }
  }
}

// ---------------- K4: proj GEMM, LDS-staged m97-style ----------------
// out[384 x 256] = wp[384 x 1024] @ act[b]^T. 128m x 128n tiles (3x2 = 6/batch),
// 4 waves 2x2, BK=64, 16 K-steps; global_load_lds w=16 + XOR-preswizzled source.
__global__ __launch_bounds__(256, 3) void k_proj(const bf16* __restrict__ act,
    const bf16* __restrict__ Wp, const float* __restrict__ proj_b,
    int b_base, int nb, float* __restrict__ out) {
  __shared__ __align__(16) char smem[32768];   // A 16K + B 16K
  bf16* sA = (bf16*)smem;                      // [128][64]
  bf16* sB = (bf16*)(smem + 16384);            // [128][64]

  int id = blockIdx.x;
  int b, tile;
  if ((nb & 7) == 0) {
    int per = nb >> 3;
    int xcd = id & 7, slot = id >> 3;
    b = xcd * per + (slot % per);
    tile = slot / per;          // [0,6)
  } else { b = id / 6; tile = id % 6; }
  int mt = tile >> 1, nt = tile & 1;
  int m0 = mt * 128, n0b = nt * 128;
  int bg = b_base + b;
  int t = threadIdx.x;
  int wave = t >> 6, lane = t & 63;
  int wm = wave >> 1, wn = wave & 1;
  int qd = lane >> 4, li = lane & 15;
  const bf16* actb = act + ((size_t)b * NTOK + n0b) * DH;

  f32x4 acc[4][4];
#pragma unroll
  for (int r = 0; r < 4; ++r)
#pragma unroll
    for (int f = 0; f < 4; ++f) acc[r][f] = (f32x4){0.f, 0.f, 0.f, 0.f};

  for (int ks = 0; ks < 16; ++ks) {
    int k0 = ks * 64;
    __syncthreads();            // prev compute done -> safe to overwrite LDS
#pragma unroll
    for (int i = 0; i < 8; ++i) {
      int g = wave * 512 + i * 64 + lane;      // [0,2048) granules; <1024 -> A
      int gg = g & 1023;
      int row = gg >> 3, slot = gg & 7;
      int col = ((slot ^ (row & 7)) << 3) + k0;
      const bf16* src = (g < 1024)
          ? (Wp + (size_t)(m0 + row) * DH + col)
          : (actb + (size_t)row * DH + col);
      GLOAD_LDS16(src, smem + (size_t)(wave * 512 + i * 64) * 16);
    }
    __syncthreads();            // staging drained (vmcnt(0) at barrier)
#pragma unroll
    for (int s = 0; s < 2; ++s) {
      bf16v8 Afr[4], Bfr[4];
#pragma unroll
      for (int r = 0; r < 4; ++r) {
        int row = wm * 64 + r * 16 + li;
        Afr[r] = *(const bf16v8*)(sA + row * 64 + (((s * 4 + qd) ^ (row & 7)) << 3));
      }
#pragma unroll
      for (int f = 0; f < 4; ++f) {
        int row = wn * 64 + f * 16 + li;
        Bfr[f] = *(const bf16v8*)(sB + row * 64 + (((s * 4 + qd) ^ (row & 7)) << 3));
      }
#pragma unroll
      for (int r = 0; r < 4; ++r)
#pragma unroll
        for (int f = 0; f < 4; ++f)
          acc[r][f] = __builtin_amdgcn_mfma_f32_16x16x32_bf16(Afr[r], Bfr[f], acc[r][f], 0, 0, 0);
    }
  }

#pragma unroll
  for (int r = 0; r < 4; ++r)
#pragma unroll
    for (int f = 0; f < 4; ++f) {
      int n = n0b + wn * 64 + f * 16 + li;
#pragma unroll
      for (int rr = 0; rr < 4; ++rr) {
        int dim = m0 + wm * 64 + r * 16 + qd * 4 + rr;
        out[((size_t)bg * DIM + dim) * NTOK + n] = acc[r][f][rr] + sf(proj_b[dim]);
      }
    }
}

extern "C" void kernel_launch(void* const* d_in, const int* in_sizes, int n_in,
                              void* d_out, int out_size, void* d_ws, size_t ws_size,
                              hipStream_t stream) {
  const float* x      = (const float*)d_in[0];
  const float* q_w    = (const float*)d_in[1];
  const float* q_b    = (const float*)d_in[2];
  const float* k_w    = (const float*)d_in[3];
  const float* k_b    = (const float*)d_in[4];
  const float* v_w    = (const float*)d_in[5];
  const float* v_b    = (const float*)d_in[6];
  const float* vl_w   = (const float*)d_in[7];
  const float* vl_b   = (const float*)d_in[8];
  const float* th1_w  = (const float*)d_in[9];
  const float* th1_b  = (const float*)d_in[10];
  const float* th2_w  = (const float*)d_in[11];
  const float* th2_b  = (const float*)d_in[12];
  const float* proj_w = (const float*)d_in[13];
  const float* proj_b = (const float*)d_in[14];
  const float* attn_b = (const float*)d_in[15];
  const int*   idxs   = (const int*)d_in[16];
  int n_off = in_sizes[15] / NH;
  float* out = (float*)d_out;

  const size_t WQ = 98304, WK = 98304, WV = 393216, WP = 393216;
  const size_t WTOT = WQ + WK + WV + WP;                       // 983040 elem
  const size_t BFULL = (size_t)NH * NTOK * NTOK;               // 524288 f32
  const size_t PB_XT = (size_t)NTOK * DIM;                     // 98304
  const size_t PB_QK = (size_t)NH * NTOK * KD;                 // 65536
  const size_t PB_V  = (size_t)DH * NTOK;                      // 262144
  const size_t PB_AC = (size_t)NTOK * DH;                      // 262144
  const size_t PB_P  = (size_t)NH * NTOK * NTOK;               // 524288
  const size_t perb  = (PB_XT + 2 * PB_QK + PB_V + PB_AC + PB_P) * 2;  // 2555904 B
  const size_t fixed = WTOT * 2 + BFULL * 4;

  char* w = (char*)d_ws;
  bf16* wcvt = (bf16*)w;  w += WTOT * 2;
  bf16* wq = wcvt;
  bf16* wk = wcvt + WQ;
  bf16* wv = wcvt + WQ + WK;
  bf16* wp = wcvt + WQ + WK + WV;
  float* bias_full = (float*)w;  w += BFULL * 4;

  size_t rem = (ws_size > fixed) ? (ws_size - fixed) : 0;
  int CH = (int)(rem / perb);
  if (CH > BB) CH = BB;
  if (CH >= 8) CH &= ~7;      // multiple of 8 -> XCD swizzle active
  if (CH < 1) CH = 1;

  bf16* xT  = (bf16*)w;  w += (size_t)CH * PB_XT * 2;
  bf16* qT  = (bf16*)w;  w += (size_t)CH * PB_QK * 2;
  bf16* kT  = (bf16*)w;  w += (size_t)CH * PB_QK * 2;
  bf16* v4  = (bf16*)w;  w += (size_t)CH * PB_V * 2;
  bf16* act = (bf16*)w;  w += (size_t)CH * PB_AC * 2;
  bf16* P   = (bf16*)w;  w += (size_t)CH * PB_P * 2;

  k_convert<<<(int)(WTOT / 256), 256, 0, stream>>>(q_w, k_w, v_w, proj_w, wcvt);
  k_bias<<<256, 256, 0, stream>>>(attn_b, idxs, n_off, th1_w, th1_b, bias_full);

  for (int c0 = 0; c0 < BB; c0 += CH) {
    int cb = (BB - c0 < CH) ? (BB - c0) : CH;
    k_transpose_x<<<dim3(12, 8, cb), 256, 0, stream>>>(x + (size_t)c0 * DIM * NTOK, xT);
    k_qkv<<<cb * 24, 256, 0, stream>>>(xT, wcvt, q_b, k_b, v_b, qT, kT, v4, cb);
    k_scores<<<cb * 16, 1024, 0, stream>>>(qT, kT, bias_full,
                                           th1_w, th2_w, th2_b, P, cb);
    k_pv<<<cb * 16 / 2, 512, 0, stream>>>(P, v4, vl_w, vl_b, act, cb);
    k_proj<<<cb * 6, 256, 0, stream>>>(act, wp, proj_b, c0, cb, out);
  }
}